// Round 4
// baseline (335.258 us; speedup 1.0000x reference)
//
#include <hip/hip_runtime.h>
#include <hip/hip_fp16.h>
#include <math.h>

#define NPTS 4096
#define CDIM 128
#define FH 120
#define FW 160
#define PIX (FH * FW)   // 19200

typedef __attribute__((ext_vector_type(8))) short short8_t;
typedef __attribute__((ext_vector_type(4))) float float4_t;
typedef __attribute__((ext_vector_type(2))) unsigned short ushort2_t;

// workspace layout (float offsets)
#define OFF_D1B   0                    // 2*4096*128 bf16 = 524288 floats
#define OFF_WDB   524288
#define OFF_JA    1048576              // float4/pt: (ky,kx,wky,wkx)
#define OFF_JB    1081344              // float2/pt: (|d1|^2, |wd|^2)
#define OFF_POS   1097728
#define OFF_VIS   1105920
#define OFF_ACC   1114112              // pad to 16
#define OFF_PARTS 1114128              // 2 halves * 24 lists * 8192 anchors
#define OFF_D2T   1507344              // fp16 transposed desc2: 2*19200*128 half
#define OFF_END   3964944

__device__ __forceinline__ unsigned short f2bf(float f) {
  unsigned int u = __float_as_uint(f);
  u = (u + 0x7fffu + ((u >> 16) & 1u)) >> 16;  // RNE, no NaN in this data
  return (unsigned short)u;
}

__device__ __forceinline__ float wavesum(float v) {
#pragma unroll
  for (int off = 1; off < 64; off <<= 1) v += __shfl_xor(v, off, 64);
  return v;
}

// ---- desc2 [b][c][pix] f32  ->  [b][pix][c] f16 ----
__global__ __launch_bounds__(256) void transpose_desc2(
    const float* __restrict__ d2, unsigned short* __restrict__ out) {
  __shared__ unsigned short tile[64][130];
  const int bp = blockIdx.x;            // 0..599
  const int b = bp / 300;
  const int p0 = (bp - b * 300) * 64;
  const int tid = threadIdx.x;
  const int grp = tid >> 6, lp = tid & 63;
#pragma unroll 4
  for (int r = 0; r < 32; ++r) {
    int c = (r << 2) | grp;
    float v = d2[((size_t)b * CDIM + c) * PIX + p0 + lp];
    tile[lp][c] = __half_as_ushort(__float2half(v));
  }
  __syncthreads();
  unsigned int* ob = (unsigned int*)(out + ((size_t)b * PIX + p0) * CDIM);
#pragma unroll
  for (int i = 0; i < 16; ++i) {
    int u = (i << 8) | tid;             // 0..4095 uint slots
    int p = u >> 6, cc = (u & 63) << 1;
    unsigned int lo = tile[p][cc], hi = tile[p][cc + 1];
    ob[u] = lo | (hi << 16);
  }
}

// one wave per point; lane handles channels (2*lane, 2*lane+1)
__global__ __launch_bounds__(256) void prep_t(
    const float* __restrict__ kp1, const float* __restrict__ wkp1,
    const float* __restrict__ desc, const unsigned short* __restrict__ desc2t,
    const float* __restrict__ homo,
    unsigned short* __restrict__ d1b, unsigned short* __restrict__ wdb,
    float4* __restrict__ jA, float2* __restrict__ jB,
    float* __restrict__ pos, float* __restrict__ vis) {
  const int tid = threadIdx.x;
  const int p = blockIdx.x * 4 + (tid >> 6);   // 0..8191
  const int lane = tid & 63;
  const int b = p >> 12;
  const int c2 = lane * 2;

  float2 v = *(const float2*)(desc + (size_t)p * CDIM + c2);
  float ss = wavesum(v.x * v.x + v.y * v.y);
  float inv = 1.0f / (sqrtf(ss) + 1e-8f);
  float d0 = v.x * inv, d1v = v.y * inv;
  ushort2_t st; st.x = f2bf(d0); st.y = f2bf(d1v);
  *(ushort2_t*)(d1b + (size_t)p * CDIM + c2) = st;
  float n1 = ss * inv * inv;

  float y = wkp1[p * 2 + 0], x = wkp1[p * 2 + 1];
  float gy = fminf(fmaxf(y * 0.125f - 0.5f, 0.0f), (float)(FH - 1));
  float gx = fminf(fmaxf(x * 0.125f - 0.5f, 0.0f), (float)(FW - 1));
  int y0 = (int)floorf(gy); y0 = min(max(y0, 0), FH - 2);
  int x0 = (int)floorf(gx); x0 = min(max(x0, 0), FW - 2);
  float wy = gy - (float)y0, wx = gx - (float)x0;
  float w00 = (1 - wy) * (1 - wx), w01 = (1 - wy) * wx;
  float w10 = wy * (1 - wx), w11 = wy * wx;
  const unsigned int* t00 = (const unsigned int*)
      (desc2t + ((size_t)b * PIX + y0 * FW + x0) * CDIM) + lane;
  unsigned int u00 = t00[0], u01 = t00[64];
  unsigned int u10 = t00[FW * 64], u11 = t00[FW * 64 + 64];
  float2 f00 = __half22float2(*(const __half2*)&u00);
  float2 f01 = __half22float2(*(const __half2*)&u01);
  float2 f10 = __half22float2(*(const __half2*)&u10);
  float2 f11 = __half22float2(*(const __half2*)&u11);
  float wv0 = f00.x * w00 + f01.x * w01 + f10.x * w10 + f11.x * w11;
  float wv1 = f00.y * w00 + f01.y * w01 + f10.y * w10 + f11.y * w11;
  float ss2 = wavesum(wv0 * wv0 + wv1 * wv1);
  float inv2 = 1.0f / (sqrtf(ss2) + 1e-8f);
  float e0 = wv0 * inv2, e1 = wv1 * inv2;
  ushort2_t sw; sw.x = f2bf(e0); sw.y = f2bf(e1);
  *(ushort2_t*)(wdb + (size_t)p * CDIM + c2) = sw;
  float n2 = ss2 * inv2 * inv2;

  float dd0 = d0 - e0, dd1 = d1v - e1;
  float ssp = wavesum(dd0 * dd0 + dd1 * dd1);

  if (lane == 0) {
    pos[p] = sqrtf(ssp + 1e-12f);
    float ky = kp1[p * 2 + 0], kx = kp1[p * 2 + 1];
    jA[p] = make_float4(ky, kx, y, x);
    jB[p] = make_float2(n1, n2);
    const float* h = homo + b * 9;
    float t0 = h[0] * kx + h[1] * ky + h[2];
    float t1 = h[3] * kx + h[4] * ky + h[5];
    float t2 = h[6] * kx + h[7] * ky + h[8];
    float qx = t0 / (t2 + 1e-8f), qy = t1 / (t2 + 1e-8f);
    vis[p] = (qx >= 0.0f && qx < 1280.0f && qy >= 0.0f && qy < 960.0f) ? 1.0f : 0.0f;
  }
}

// fallback prep (direct fp32 gather) when ws too small for the transpose
__global__ __launch_bounds__(256) void prep_g(
    const float* __restrict__ kp1, const float* __restrict__ wkp1,
    const float* __restrict__ desc, const float* __restrict__ desc2,
    const float* __restrict__ homo,
    unsigned short* __restrict__ d1b, unsigned short* __restrict__ wdb,
    float4* __restrict__ jA, float2* __restrict__ jB,
    float* __restrict__ pos, float* __restrict__ vis) {
  const int tid = threadIdx.x;
  const int p = blockIdx.x * 4 + (tid >> 6);
  const int lane = tid & 63;
  const int b = p >> 12;
  const int c2 = lane * 2;

  float2 v = *(const float2*)(desc + (size_t)p * CDIM + c2);
  float ss = wavesum(v.x * v.x + v.y * v.y);
  float inv = 1.0f / (sqrtf(ss) + 1e-8f);
  float d0 = v.x * inv, d1v = v.y * inv;
  ushort2_t st; st.x = f2bf(d0); st.y = f2bf(d1v);
  *(ushort2_t*)(d1b + (size_t)p * CDIM + c2) = st;
  float n1 = ss * inv * inv;

  float y = wkp1[p * 2 + 0], x = wkp1[p * 2 + 1];
  float gy = fminf(fmaxf(y * 0.125f - 0.5f, 0.0f), (float)(FH - 1));
  float gx = fminf(fmaxf(x * 0.125f - 0.5f, 0.0f), (float)(FW - 1));
  int y0 = (int)floorf(gy); y0 = min(max(y0, 0), FH - 2);
  int x0 = (int)floorf(gx); x0 = min(max(x0, 0), FW - 2);
  float wy = gy - (float)y0, wx = gx - (float)x0;
  float w00 = (1 - wy) * (1 - wx), w01 = (1 - wy) * wx;
  float w10 = wy * (1 - wx), w11 = wy * wx;
  const float* q0 = desc2 + ((size_t)b * CDIM + c2) * PIX + y0 * FW + x0;
  const float* q1 = q0 + PIX;
  float wv0 = q0[0] * w00 + q0[1] * w01 + q0[FW] * w10 + q0[FW + 1] * w11;
  float wv1 = q1[0] * w00 + q1[1] * w01 + q1[FW] * w10 + q1[FW + 1] * w11;
  float ss2 = wavesum(wv0 * wv0 + wv1 * wv1);
  float inv2 = 1.0f / (sqrtf(ss2) + 1e-8f);
  float e0 = wv0 * inv2, e1 = wv1 * inv2;
  ushort2_t sw; sw.x = f2bf(e0); sw.y = f2bf(e1);
  *(ushort2_t*)(wdb + (size_t)p * CDIM + c2) = sw;
  float n2 = ss2 * inv2 * inv2;

  float dd0 = d0 - e0, dd1 = d1v - e1;
  float ssp = wavesum(dd0 * dd0 + dd1 * dd1);

  if (lane == 0) {
    pos[p] = sqrtf(ssp + 1e-12f);
    float ky = kp1[p * 2 + 0], kx = kp1[p * 2 + 1];
    jA[p] = make_float4(ky, kx, y, x);
    jB[p] = make_float2(n1, n2);
    const float* h = homo + b * 9;
    float t0 = h[0] * kx + h[1] * ky + h[2];
    float t1 = h[3] * kx + h[4] * ky + h[5];
    float t2 = h[6] * kx + h[7] * ky + h[8];
    float qx = t0 / (t2 + 1e-8f), qy = t1 / (t2 + 1e-8f);
    vis[p] = (qx >= 0.0f && qx < 1280.0f && qy >= 0.0f && qy < 960.0f) ? 1.0f : 0.0f;
  }
}

// descending insert, caller guards v > L[last]
__device__ __forceinline__ void ins6d(float v, float* L) {
  float cv = v;
#pragma unroll
  for (int k = 0; k < 6; ++k) {
    float o = L[k];
    bool gt = cv > o;
    L[k] = gt ? cv : o;
    cv = gt ? o : cv;
  }
}
__device__ __forceinline__ void ins10d(float v, float* L) {
  float cv = v;
#pragma unroll
  for (int k = 0; k < 10; ++k) {
    float o = L[k];
    bool gt = cv > o;
    L[k] = gt ? cv : o;
    cv = gt ? o : cv;
  }
}

// pack j (12 bits) into low mantissa of score; float ordering preserved to ~2^-12
__device__ __forceinline__ float packkey(float s, int j) {
  return __uint_as_float((__float_as_uint(s) & 0xFFFFF000u) | (unsigned)j);
}

// 1024 blocks x 512 threads (8 waves). Block = (batch, 16 anchors, j-half).
// Wave w sweeps 256 j in its half. Partial lists -> parts[half][list][anchor].
__global__ __launch_bounds__(512, 6) void loss_main(
    const unsigned short* __restrict__ d1b, const unsigned short* __restrict__ wdb,
    const float2* __restrict__ jBg, float* __restrict__ parts) {
  __shared__ float mb[8][16][24];   // ladder merge buffer

  const int tid = threadIdx.x;
  const int bid = blockIdx.x;
  const int b = bid & 1;
  const int half = (bid >> 1) & 1;
  const int g = bid >> 2;                 // 0..255
  const int i0 = g * 16;
  const int wave = tid >> 6, lane = tid & 63;
  const int c = lane & 15;                // anchor class (N)
  const int quad = lane >> 4;
  const int base = b * NPTS;

  // B fragments: the 16 anchors' descriptors, resident for the whole sweep
  short8_t Bd[4], Bw[4];
  {
    const unsigned short* pa = d1b + (size_t)(base + i0 + c) * CDIM + quad * 8;
    const unsigned short* pw = wdb + (size_t)(base + i0 + c) * CDIM + quad * 8;
#pragma unroll
    for (int kc = 0; kc < 4; ++kc) {
      Bd[kc] = *(const short8_t*)(pa + kc * 32);
      Bw[kc] = *(const short8_t*)(pw + kc * 32);
    }
  }

  float fD[6], fDt[6], fS[10];
#pragma unroll
  for (int k = 0; k < 6; ++k) { fD[k] = -1e30f; fDt[k] = -1e30f; }
#pragma unroll
  for (int k = 0; k < 10; ++k) fS[k] = -1e30f;

  const int jbase0 = (half << 11) | (wave << 8);
  for (int t = 0; t < 16; ++t) {
    const int j0 = jbase0 + (t << 4);
    const unsigned short* pj1 = d1b + (size_t)(base + j0 + c) * CDIM + quad * 8;
    const unsigned short* pj2 = wdb + (size_t)(base + j0 + c) * CDIM + quad * 8;
    short8_t Ad[4], Aw[4];
#pragma unroll
    for (int kc = 0; kc < 4; ++kc) {
      Ad[kc] = *(const short8_t*)(pj1 + kc * 32);
      Aw[kc] = *(const short8_t*)(pj2 + kc * 32);
    }
    float2 jn[4];
#pragma unroll
    for (int reg = 0; reg < 4; ++reg) jn[reg] = jBg[base + j0 + (quad << 2) + reg];

    float4_t aD = {0, 0, 0, 0}, aDt = {0, 0, 0, 0}, a11 = {0, 0, 0, 0};
#pragma unroll
    for (int kc = 0; kc < 4; ++kc) {
      aD  = __builtin_amdgcn_mfma_f32_16x16x32_bf16(Aw[kc], Bd[kc], aD,  0, 0, 0);  // d1_i·wd_j
      aDt = __builtin_amdgcn_mfma_f32_16x16x32_bf16(Ad[kc], Bw[kc], aDt, 0, 0, 0);  // wd_i·d1_j
      a11 = __builtin_amdgcn_mfma_f32_16x16x32_bf16(Ad[kc], Bd[kc], a11, 0, 0, 0);  // d1_i·d1_j
    }

#pragma unroll
    for (int reg = 0; reg < 4; ++reg) {
      const int jj = j0 + (quad << 2) + reg;
      float kD  = packkey(fmaf(2.0f, aD[reg],  -jn[reg].y), jj);
      float kDt = packkey(fmaf(2.0f, aDt[reg], -jn[reg].x), jj);
      float k11 = packkey(fmaf(2.0f, a11[reg], -jn[reg].x), jj);
      if (kD  > fD[5])  ins6d(kD, fD);
      if (kDt > fDt[5]) ins6d(kDt, fDt);
      if (k11 > fS[9])  ins10d(k11, fS);
    }
  }

  // merge the 4 quads (same anchor class) via shfl butterfly (snapshot first)
  {
    float tmp[10];
#pragma unroll
    for (int off = 16; off <= 32; off <<= 1) {
#pragma unroll
      for (int k = 0; k < 6; ++k) tmp[k] = fD[k];
#pragma unroll
      for (int k = 0; k < 6; ++k) { float tv = __shfl_xor(tmp[k], off, 64); if (tv > fD[5]) ins6d(tv, fD); }
#pragma unroll
      for (int k = 0; k < 6; ++k) tmp[k] = fDt[k];
#pragma unroll
      for (int k = 0; k < 6; ++k) { float tv = __shfl_xor(tmp[k], off, 64); if (tv > fDt[5]) ins6d(tv, fDt); }
#pragma unroll
      for (int k = 0; k < 10; ++k) tmp[k] = fS[k];
#pragma unroll
      for (int k = 0; k < 10; ++k) { float tv = __shfl_xor(tmp[k], off, 64); if (tv > fS[9]) ins10d(tv, fS); }
    }
  }

  // ladder merge across 8 waves
#pragma unroll
  for (int h2 = 4; h2 >= 1; h2 >>= 1) {
    if (wave >= h2 && wave < 2 * h2 && lane < 16) {
      float* m = &mb[wave][lane][0];
#pragma unroll
      for (int k = 0; k < 6; ++k) { m[k] = fD[k]; m[6 + k] = fDt[k]; }
#pragma unroll
      for (int k = 0; k < 10; ++k) m[12 + k] = fS[k];
    }
    __syncthreads();
    if (wave < h2 && lane < 16) {
      const float* m = &mb[wave + h2][lane][0];
#pragma unroll
      for (int k = 0; k < 6; ++k) { float tv = m[k]; if (tv > fD[5]) ins6d(tv, fD); }
#pragma unroll
      for (int k = 0; k < 6; ++k) { float tv = m[6 + k]; if (tv > fDt[5]) ins6d(tv, fDt); }
#pragma unroll
      for (int k = 0; k < 10; ++k) { float tv = m[12 + k]; if (tv > fS[9]) ins10d(tv, fS); }
    }
  }

  if (wave == 0 && lane < 16) {
    float* P = parts + (size_t)(half * 24) * 8192 + (base + i0 + lane);
#pragma unroll
    for (int k = 0; k < 6; ++k) {
      P[(size_t)k * 8192] = fD[k];
      P[(size_t)(6 + k) * 8192] = fDt[k];
    }
#pragma unroll
    for (int k = 0; k < 10; ++k) P[(size_t)(12 + k) * 8192] = fS[k];
  }
}

__device__ __forceinline__ float bflo(unsigned int u) { return __uint_as_float(u << 16); }
__device__ __forceinline__ float bfhi(unsigned int u) { return __uint_as_float(u & 0xFFFF0000u); }

// 256 blocks x 256 threads; block = 32 anchors. Merge halves, post-filter,
// recompute d22 for SOS survivors, accumulate.
__global__ __launch_bounds__(256) void merge_filter(
    const float* __restrict__ parts, const float4* __restrict__ jAg,
    const float2* __restrict__ jBg, const float* __restrict__ posg,
    const float* __restrict__ visg, const unsigned short* __restrict__ wdb,
    float* __restrict__ accum) {
  __shared__ int sJ[256];
  __shared__ float sD11[256], sD22[256], sFos[32], sVis[32], sN2[32];
  __shared__ float red[4];
  const int tid = threadIdx.x;
  const int a0 = blockIdx.x * 32;

  if (tid < 32) {
    const int a = a0 + tid;
    const int base = a & ~(NPTS - 1);
    float fD[6], fDt[6], fS[10];
    const float* P0 = parts + a;
    const float* P1 = parts + (size_t)24 * 8192 + a;
#pragma unroll
    for (int k = 0; k < 6; ++k) { fD[k] = P0[(size_t)k * 8192]; fDt[k] = P0[(size_t)(6 + k) * 8192]; }
#pragma unroll
    for (int k = 0; k < 10; ++k) fS[k] = P0[(size_t)(12 + k) * 8192];
#pragma unroll
    for (int k = 0; k < 6; ++k) {
      float v = P1[(size_t)k * 8192]; if (v > fD[5]) ins6d(v, fD);
      float w = P1[(size_t)(6 + k) * 8192]; if (w > fDt[5]) ins6d(w, fDt);
    }
#pragma unroll
    for (int k = 0; k < 10; ++k) {
      float v = P1[(size_t)(12 + k) * 8192]; if (v > fS[9]) ins10d(v, fS);
    }

    const float4 own = jAg[a];
    const float2 nb = jBg[a];
    const float pv = posg[a], vv = visg[a];
    float t1s = 0.0f, t2s = 0.0f;
    int got = 0;
#pragma unroll
    for (int k = 0; k < 6; ++k) {
      int j = (int)(__float_as_uint(fD[k]) & 0xFFFu);
      float4 jc = jAg[base + j];
      float dz = own.z - jc.z, dw = own.w - jc.w;
      if (got < 4 && dz * dz + dw * dw > 256.0f) {
        float d2 = nb.x - fD[k];
        t1s += fmaxf(1.0f + pv - sqrtf(fmaxf(d2, 1e-12f)), 0.0f);
        got++;
      }
    }
    got = 0;
#pragma unroll
    for (int k = 0; k < 6; ++k) {
      int j = (int)(__float_as_uint(fDt[k]) & 0xFFFu);
      float4 jc = jAg[base + j];
      float dz = own.z - jc.z, dw = own.w - jc.w;
      if (got < 4 && dz * dz + dw * dw > 256.0f) {
        float d2 = nb.y - fDt[k];
        t2s += fmaxf(1.0f + pv - sqrtf(fmaxf(d2, 1e-12f)), 0.0f);
        got++;
      }
    }
    int m = 0;
#pragma unroll
    for (int k = 0; k < 10; ++k) {
      int j = (int)(__float_as_uint(fS[k]) & 0xFFFu);
      float4 jc = jAg[base + j];
      float ay = own.x - jc.x, ax = own.y - jc.y;
      float wz = own.z - jc.z, ww = own.w - jc.w;
      if (m < 8 && ay * ay + ax * ax > 256.0f && wz * wz + ww * ww > 256.0f) {
        sJ[tid * 8 + m] = base + j;
        sD11[tid * 8 + m] = sqrtf(fmaxf(nb.x - fS[k], 1e-12f));
        m++;
      }
    }
    for (int k = m; k < 8; ++k) sJ[tid * 8 + k] = -1;
    sFos[tid] = vv * 0.125f * (t1s + t2s);
    sVis[tid] = vv;
    sN2[tid] = nb.y;
  }
  __syncthreads();

  // d22 for survivors: 256 slots, one thread each
  {
    const int slot = tid;
    const int al = slot >> 3;
    const int j = sJ[slot];
    float d22 = 0.0f;
    if (j >= 0) {
      const uint4* pi = (const uint4*)(wdb + (size_t)(a0 + al) * CDIM);
      const uint4* pj = (const uint4*)(wdb + (size_t)j * CDIM);
      float dot = 0.0f;
#pragma unroll
      for (int q = 0; q < 16; ++q) {
        uint4 ui = pi[q], uj = pj[q];
        dot = fmaf(bflo(ui.x), bflo(uj.x), dot); dot = fmaf(bfhi(ui.x), bfhi(uj.x), dot);
        dot = fmaf(bflo(ui.y), bflo(uj.y), dot); dot = fmaf(bfhi(ui.y), bfhi(uj.y), dot);
        dot = fmaf(bflo(ui.z), bflo(uj.z), dot); dot = fmaf(bfhi(ui.z), bfhi(uj.z), dot);
        dot = fmaf(bflo(ui.w), bflo(uj.w), dot); dot = fmaf(bfhi(ui.w), bfhi(uj.w), dot);
      }
      d22 = sqrtf(fmaxf(sN2[al] + jBg[j].y - 2.0f * dot, 1e-12f));
    }
    sD22[slot] = d22;
  }
  __syncthreads();

  float contrib = 0.0f;
  if (tid < 32) {
    float s = 0.0f;
#pragma unroll
    for (int k = 0; k < 8; ++k) {
      if (sJ[tid * 8 + k] >= 0) {
        float d = sD11[tid * 8 + k] - sD22[tid * 8 + k];
        s = fmaf(d, d, s);
      }
    }
    contrib = sFos[tid] + sVis[tid] * sqrtf(s + 1e-12f);
  }
#pragma unroll
  for (int off = 32; off >= 1; off >>= 1) contrib += __shfl_down(contrib, off, 64);
  if ((tid & 63) == 0) red[tid >> 6] = contrib;
  __syncthreads();
  if (tid == 0) atomicAdd(&accum[0], red[0] + red[1] + red[2] + red[3]);
}

__global__ __launch_bounds__(256) void finalize_kernel(
    const float* __restrict__ vis, const float* __restrict__ acc,
    float* __restrict__ out) {
  __shared__ float red[4];
  float s = 0.0f;
  for (int i = threadIdx.x; i < 2 * NPTS; i += 256) s += vis[i];
#pragma unroll
  for (int off = 32; off >= 1; off >>= 1) s += __shfl_down(s, off, 64);
  if ((threadIdx.x & 63) == 0) red[threadIdx.x >> 6] = s;
  __syncthreads();
  if (threadIdx.x == 0) {
    float denom = red[0] + red[1] + red[2] + red[3] + 1e-8f;
    out[0] = acc[0] / denom;
  }
}

extern "C" void kernel_launch(void* const* d_in, const int* in_sizes, int n_in,
                              void* d_out, int out_size, void* d_ws, size_t ws_size,
                              hipStream_t stream) {
  (void)in_sizes; (void)n_in; (void)out_size;
  const float* kp1   = (const float*)d_in[0];
  const float* wkp1  = (const float*)d_in[1];
  const float* desc  = (const float*)d_in[2];
  const float* desc2 = (const float*)d_in[3];
  const float* homo  = (const float*)d_in[4];
  float* ws = (float*)d_ws;
  unsigned short* d1b = (unsigned short*)(ws + OFF_D1B);
  unsigned short* wdb = (unsigned short*)(ws + OFF_WDB);
  float4* jA = (float4*)(ws + OFF_JA);
  float2* jB = (float2*)(ws + OFF_JB);
  float* pos = ws + OFF_POS;
  float* vis = ws + OFF_VIS;
  float* acc = ws + OFF_ACC;
  float* parts = ws + OFF_PARTS;
  unsigned short* d2t = (unsigned short*)(ws + OFF_D2T);

  hipMemsetAsync(acc, 0, 2 * sizeof(float), stream);
  if (ws_size >= (size_t)OFF_END * 4) {
    transpose_desc2<<<600, 256, 0, stream>>>(desc2, d2t);
    prep_t<<<2048, 256, 0, stream>>>(kp1, wkp1, desc, d2t, homo,
                                     d1b, wdb, jA, jB, pos, vis);
  } else {
    prep_g<<<2048, 256, 0, stream>>>(kp1, wkp1, desc, desc2, homo,
                                     d1b, wdb, jA, jB, pos, vis);
  }
  loss_main<<<1024, 512, 0, stream>>>(d1b, wdb, jB, parts);
  merge_filter<<<256, 256, 0, stream>>>(parts, jA, jB, pos, vis, wdb, acc);
  finalize_kernel<<<1, 256, 0, stream>>>(vis, acc, (float*)d_out);
}

// Round 5
// 279.616 us; speedup vs baseline: 1.1990x; 1.1990x over previous
//
#include <hip/hip_runtime.h>
#include <hip/hip_fp16.h>
#include <math.h>

#define NPTS 4096
#define CDIM 128
#define FH 120
#define FW 160
#define PIX (FH * FW)   // 19200

typedef __attribute__((ext_vector_type(8))) short short8_t;
typedef __attribute__((ext_vector_type(4))) float float4_t;
typedef __attribute__((ext_vector_type(2))) unsigned short ushort2_t;

// workspace layout (float offsets)
#define OFF_D1B   0                    // 2*4096*128 bf16 = 524288 floats
#define OFF_WDB   524288
#define OFF_JA    1048576              // float4/pt: (ky,kx,wky,wkx)
#define OFF_JB    1081344              // float2/pt: (|d1|^2, |wd|^2)
#define OFF_POS   1097728
#define OFF_VIS   1105920
#define OFF_ACC   1114112              // pad to 16
#define OFF_PARTS 1114128              // 2 halves * 24 lists * 8192 anchors
#define OFF_D2T   1507344              // fp16 transposed desc2: 2*19200*128 half
#define OFF_END   3964944

__device__ __forceinline__ unsigned short f2bf(float f) {
  unsigned int u = __float_as_uint(f);
  u = (u + 0x7fffu + ((u >> 16) & 1u)) >> 16;  // RNE, no NaN in this data
  return (unsigned short)u;
}

__device__ __forceinline__ float wavesum(float v) {
#pragma unroll
  for (int off = 1; off < 64; off <<= 1) v += __shfl_xor(v, off, 64);
  return v;
}

// ---- desc2 [b][c][pix] f32  ->  [b][pix][c] f16 ----
__global__ __launch_bounds__(256) void transpose_desc2(
    const float* __restrict__ d2, unsigned short* __restrict__ out) {
  __shared__ unsigned short tile[64][130];
  const int bp = blockIdx.x;            // 0..599
  const int b = bp / 300;
  const int p0 = (bp - b * 300) * 64;
  const int tid = threadIdx.x;
  const int grp = tid >> 6, lp = tid & 63;
#pragma unroll 4
  for (int r = 0; r < 32; ++r) {
    int c = (r << 2) | grp;
    float v = d2[((size_t)b * CDIM + c) * PIX + p0 + lp];
    tile[lp][c] = __half_as_ushort(__float2half(v));
  }
  __syncthreads();
  unsigned int* ob = (unsigned int*)(out + ((size_t)b * PIX + p0) * CDIM);
#pragma unroll
  for (int i = 0; i < 16; ++i) {
    int u = (i << 8) | tid;             // 0..4095 uint slots
    int p = u >> 6, cc = (u & 63) << 1;
    unsigned int lo = tile[p][cc], hi = tile[p][cc + 1];
    ob[u] = lo | (hi << 16);
  }
}

// one wave per point; lane handles channels (2*lane, 2*lane+1)
__global__ __launch_bounds__(256) void prep_t(
    const float* __restrict__ kp1, const float* __restrict__ wkp1,
    const float* __restrict__ desc, const unsigned short* __restrict__ desc2t,
    const float* __restrict__ homo,
    unsigned short* __restrict__ d1b, unsigned short* __restrict__ wdb,
    float4* __restrict__ jA, float2* __restrict__ jB,
    float* __restrict__ pos, float* __restrict__ vis) {
  const int tid = threadIdx.x;
  const int p = blockIdx.x * 4 + (tid >> 6);   // 0..8191
  const int lane = tid & 63;
  const int b = p >> 12;
  const int c2 = lane * 2;

  float2 v = *(const float2*)(desc + (size_t)p * CDIM + c2);
  float ss = wavesum(v.x * v.x + v.y * v.y);
  float inv = 1.0f / (sqrtf(ss) + 1e-8f);
  float d0 = v.x * inv, d1v = v.y * inv;
  ushort2_t st; st.x = f2bf(d0); st.y = f2bf(d1v);
  *(ushort2_t*)(d1b + (size_t)p * CDIM + c2) = st;
  float n1 = ss * inv * inv;

  float y = wkp1[p * 2 + 0], x = wkp1[p * 2 + 1];
  float gy = fminf(fmaxf(y * 0.125f - 0.5f, 0.0f), (float)(FH - 1));
  float gx = fminf(fmaxf(x * 0.125f - 0.5f, 0.0f), (float)(FW - 1));
  int y0 = (int)floorf(gy); y0 = min(max(y0, 0), FH - 2);
  int x0 = (int)floorf(gx); x0 = min(max(x0, 0), FW - 2);
  float wy = gy - (float)y0, wx = gx - (float)x0;
  float w00 = (1 - wy) * (1 - wx), w01 = (1 - wy) * wx;
  float w10 = wy * (1 - wx), w11 = wy * wx;
  const unsigned int* t00 = (const unsigned int*)
      (desc2t + ((size_t)b * PIX + y0 * FW + x0) * CDIM) + lane;
  unsigned int u00 = t00[0], u01 = t00[64];
  unsigned int u10 = t00[FW * 64], u11 = t00[FW * 64 + 64];
  float2 f00 = __half22float2(*(const __half2*)&u00);
  float2 f01 = __half22float2(*(const __half2*)&u01);
  float2 f10 = __half22float2(*(const __half2*)&u10);
  float2 f11 = __half22float2(*(const __half2*)&u11);
  float wv0 = f00.x * w00 + f01.x * w01 + f10.x * w10 + f11.x * w11;
  float wv1 = f00.y * w00 + f01.y * w01 + f10.y * w10 + f11.y * w11;
  float ss2 = wavesum(wv0 * wv0 + wv1 * wv1);
  float inv2 = 1.0f / (sqrtf(ss2) + 1e-8f);
  float e0 = wv0 * inv2, e1 = wv1 * inv2;
  ushort2_t sw; sw.x = f2bf(e0); sw.y = f2bf(e1);
  *(ushort2_t*)(wdb + (size_t)p * CDIM + c2) = sw;
  float n2 = ss2 * inv2 * inv2;

  float dd0 = d0 - e0, dd1 = d1v - e1;
  float ssp = wavesum(dd0 * dd0 + dd1 * dd1);

  if (lane == 0) {
    pos[p] = sqrtf(ssp + 1e-12f);
    float ky = kp1[p * 2 + 0], kx = kp1[p * 2 + 1];
    jA[p] = make_float4(ky, kx, y, x);
    jB[p] = make_float2(n1, n2);
    const float* h = homo + b * 9;
    float t0 = h[0] * kx + h[1] * ky + h[2];
    float t1 = h[3] * kx + h[4] * ky + h[5];
    float t2 = h[6] * kx + h[7] * ky + h[8];
    float qx = t0 / (t2 + 1e-8f), qy = t1 / (t2 + 1e-8f);
    vis[p] = (qx >= 0.0f && qx < 1280.0f && qy >= 0.0f && qy < 960.0f) ? 1.0f : 0.0f;
  }
}

// fallback prep (direct fp32 gather) when ws too small for the transpose
__global__ __launch_bounds__(256) void prep_g(
    const float* __restrict__ kp1, const float* __restrict__ wkp1,
    const float* __restrict__ desc, const float* __restrict__ desc2,
    const float* __restrict__ homo,
    unsigned short* __restrict__ d1b, unsigned short* __restrict__ wdb,
    float4* __restrict__ jA, float2* __restrict__ jB,
    float* __restrict__ pos, float* __restrict__ vis) {
  const int tid = threadIdx.x;
  const int p = blockIdx.x * 4 + (tid >> 6);
  const int lane = tid & 63;
  const int b = p >> 12;
  const int c2 = lane * 2;

  float2 v = *(const float2*)(desc + (size_t)p * CDIM + c2);
  float ss = wavesum(v.x * v.x + v.y * v.y);
  float inv = 1.0f / (sqrtf(ss) + 1e-8f);
  float d0 = v.x * inv, d1v = v.y * inv;
  ushort2_t st; st.x = f2bf(d0); st.y = f2bf(d1v);
  *(ushort2_t*)(d1b + (size_t)p * CDIM + c2) = st;
  float n1 = ss * inv * inv;

  float y = wkp1[p * 2 + 0], x = wkp1[p * 2 + 1];
  float gy = fminf(fmaxf(y * 0.125f - 0.5f, 0.0f), (float)(FH - 1));
  float gx = fminf(fmaxf(x * 0.125f - 0.5f, 0.0f), (float)(FW - 1));
  int y0 = (int)floorf(gy); y0 = min(max(y0, 0), FH - 2);
  int x0 = (int)floorf(gx); x0 = min(max(x0, 0), FW - 2);
  float wy = gy - (float)y0, wx = gx - (float)x0;
  float w00 = (1 - wy) * (1 - wx), w01 = (1 - wy) * wx;
  float w10 = wy * (1 - wx), w11 = wy * wx;
  const float* q0 = desc2 + ((size_t)b * CDIM + c2) * PIX + y0 * FW + x0;
  const float* q1 = q0 + PIX;
  float wv0 = q0[0] * w00 + q0[1] * w01 + q0[FW] * w10 + q0[FW + 1] * w11;
  float wv1 = q1[0] * w00 + q1[1] * w01 + q1[FW] * w10 + q1[FW + 1] * w11;
  float ss2 = wavesum(wv0 * wv0 + wv1 * wv1);
  float inv2 = 1.0f / (sqrtf(ss2) + 1e-8f);
  float e0 = wv0 * inv2, e1 = wv1 * inv2;
  ushort2_t sw; sw.x = f2bf(e0); sw.y = f2bf(e1);
  *(ushort2_t*)(wdb + (size_t)p * CDIM + c2) = sw;
  float n2 = ss2 * inv2 * inv2;

  float dd0 = d0 - e0, dd1 = d1v - e1;
  float ssp = wavesum(dd0 * dd0 + dd1 * dd1);

  if (lane == 0) {
    pos[p] = sqrtf(ssp + 1e-12f);
    float ky = kp1[p * 2 + 0], kx = kp1[p * 2 + 1];
    jA[p] = make_float4(ky, kx, y, x);
    jB[p] = make_float2(n1, n2);
    const float* h = homo + b * 9;
    float t0 = h[0] * kx + h[1] * ky + h[2];
    float t1 = h[3] * kx + h[4] * ky + h[5];
    float t2 = h[6] * kx + h[7] * ky + h[8];
    float qx = t0 / (t2 + 1e-8f), qy = t1 / (t2 + 1e-8f);
    vis[p] = (qx >= 0.0f && qx < 1280.0f && qy >= 0.0f && qy < 960.0f) ? 1.0f : 0.0f;
  }
}

// descending insert, caller guards v > L[last]
__device__ __forceinline__ void ins6d(float v, float* L) {
  float cv = v;
#pragma unroll
  for (int k = 0; k < 6; ++k) {
    float o = L[k];
    bool gt = cv > o;
    L[k] = gt ? cv : o;
    cv = gt ? o : cv;
  }
}
__device__ __forceinline__ void ins10d(float v, float* L) {
  float cv = v;
#pragma unroll
  for (int k = 0; k < 10; ++k) {
    float o = L[k];
    bool gt = cv > o;
    L[k] = gt ? cv : o;
    cv = gt ? o : cv;
  }
}

// pack j (12 bits) into low mantissa of score; float ordering preserved to ~2^-12
__device__ __forceinline__ float packkey(float s, int j) {
  return __uint_as_float((__float_as_uint(s) & 0xFFFFF000u) | (unsigned)j);
}

// 1024 blocks x 512 threads (8 waves). Block = (batch, 16 anchors, j-half).
// Wave w sweeps 256 j in its half. Partial lists -> parts[half][list][anchor].
// launch_bounds(512,4): 128-VGPR cap — (512,6) spilled to scratch (R4: 42MB
// WRITE_SIZE, +70us). Do not raise the min-waves arg again.
__global__ __launch_bounds__(512, 4) void loss_main(
    const unsigned short* __restrict__ d1b, const unsigned short* __restrict__ wdb,
    const float2* __restrict__ jBg, float* __restrict__ parts) {
  __shared__ float mb[8][16][24];   // ladder merge buffer

  const int tid = threadIdx.x;
  const int bid = blockIdx.x;
  const int b = bid & 1;
  const int half = (bid >> 1) & 1;
  const int g = bid >> 2;                 // 0..255
  const int i0 = g * 16;
  const int wave = tid >> 6, lane = tid & 63;
  const int c = lane & 15;                // anchor class (N)
  const int quad = lane >> 4;
  const int base = b * NPTS;

  // B fragments: the 16 anchors' descriptors, resident for the whole sweep
  short8_t Bd[4], Bw[4];
  {
    const unsigned short* pa = d1b + (size_t)(base + i0 + c) * CDIM + quad * 8;
    const unsigned short* pw = wdb + (size_t)(base + i0 + c) * CDIM + quad * 8;
#pragma unroll
    for (int kc = 0; kc < 4; ++kc) {
      Bd[kc] = *(const short8_t*)(pa + kc * 32);
      Bw[kc] = *(const short8_t*)(pw + kc * 32);
    }
  }

  float fD[6], fDt[6], fS[10];
#pragma unroll
  for (int k = 0; k < 6; ++k) { fD[k] = -1e30f; fDt[k] = -1e30f; }
#pragma unroll
  for (int k = 0; k < 10; ++k) fS[k] = -1e30f;

  const int jbase0 = (half << 11) | (wave << 8);
  for (int t = 0; t < 16; ++t) {
    const int j0 = jbase0 + (t << 4);
    const unsigned short* pj1 = d1b + (size_t)(base + j0 + c) * CDIM + quad * 8;
    const unsigned short* pj2 = wdb + (size_t)(base + j0 + c) * CDIM + quad * 8;
    short8_t Ad[4], Aw[4];
#pragma unroll
    for (int kc = 0; kc < 4; ++kc) {
      Ad[kc] = *(const short8_t*)(pj1 + kc * 32);
      Aw[kc] = *(const short8_t*)(pj2 + kc * 32);
    }
    float2 jn[4];
#pragma unroll
    for (int reg = 0; reg < 4; ++reg) jn[reg] = jBg[base + j0 + (quad << 2) + reg];

    float4_t aD = {0, 0, 0, 0}, aDt = {0, 0, 0, 0}, a11 = {0, 0, 0, 0};
#pragma unroll
    for (int kc = 0; kc < 4; ++kc) {
      aD  = __builtin_amdgcn_mfma_f32_16x16x32_bf16(Aw[kc], Bd[kc], aD,  0, 0, 0);  // d1_i·wd_j
      aDt = __builtin_amdgcn_mfma_f32_16x16x32_bf16(Ad[kc], Bw[kc], aDt, 0, 0, 0);  // wd_i·d1_j
      a11 = __builtin_amdgcn_mfma_f32_16x16x32_bf16(Ad[kc], Bd[kc], a11, 0, 0, 0);  // d1_i·d1_j
    }

#pragma unroll
    for (int reg = 0; reg < 4; ++reg) {
      const int jj = j0 + (quad << 2) + reg;
      float kD  = packkey(fmaf(2.0f, aD[reg],  -jn[reg].y), jj);
      float kDt = packkey(fmaf(2.0f, aDt[reg], -jn[reg].x), jj);
      float k11 = packkey(fmaf(2.0f, a11[reg], -jn[reg].x), jj);
      if (kD  > fD[5])  ins6d(kD, fD);
      if (kDt > fDt[5]) ins6d(kDt, fDt);
      if (k11 > fS[9])  ins10d(k11, fS);
    }
  }

  // merge the 4 quads (same anchor class) via shfl butterfly (snapshot first)
  {
    float tmp[10];
#pragma unroll
    for (int off = 16; off <= 32; off <<= 1) {
#pragma unroll
      for (int k = 0; k < 6; ++k) tmp[k] = fD[k];
#pragma unroll
      for (int k = 0; k < 6; ++k) { float tv = __shfl_xor(tmp[k], off, 64); if (tv > fD[5]) ins6d(tv, fD); }
#pragma unroll
      for (int k = 0; k < 6; ++k) tmp[k] = fDt[k];
#pragma unroll
      for (int k = 0; k < 6; ++k) { float tv = __shfl_xor(tmp[k], off, 64); if (tv > fDt[5]) ins6d(tv, fDt); }
#pragma unroll
      for (int k = 0; k < 10; ++k) tmp[k] = fS[k];
#pragma unroll
      for (int k = 0; k < 10; ++k) { float tv = __shfl_xor(tmp[k], off, 64); if (tv > fS[9]) ins10d(tv, fS); }
    }
  }

  // ladder merge across 8 waves
#pragma unroll
  for (int h2 = 4; h2 >= 1; h2 >>= 1) {
    if (wave >= h2 && wave < 2 * h2 && lane < 16) {
      float* m = &mb[wave][lane][0];
#pragma unroll
      for (int k = 0; k < 6; ++k) { m[k] = fD[k]; m[6 + k] = fDt[k]; }
#pragma unroll
      for (int k = 0; k < 10; ++k) m[12 + k] = fS[k];
    }
    __syncthreads();
    if (wave < h2 && lane < 16) {
      const float* m = &mb[wave + h2][lane][0];
#pragma unroll
      for (int k = 0; k < 6; ++k) { float tv = m[k]; if (tv > fD[5]) ins6d(tv, fD); }
#pragma unroll
      for (int k = 0; k < 6; ++k) { float tv = m[6 + k]; if (tv > fDt[5]) ins6d(tv, fDt); }
#pragma unroll
      for (int k = 0; k < 10; ++k) { float tv = m[12 + k]; if (tv > fS[9]) ins10d(tv, fS); }
    }
  }

  if (wave == 0 && lane < 16) {
    float* P = parts + (size_t)(half * 24) * 8192 + (base + i0 + lane);
#pragma unroll
    for (int k = 0; k < 6; ++k) {
      P[(size_t)k * 8192] = fD[k];
      P[(size_t)(6 + k) * 8192] = fDt[k];
    }
#pragma unroll
    for (int k = 0; k < 10; ++k) P[(size_t)(12 + k) * 8192] = fS[k];
  }
}

__device__ __forceinline__ float bflo(unsigned int u) { return __uint_as_float(u << 16); }
__device__ __forceinline__ float bfhi(unsigned int u) { return __uint_as_float(u & 0xFFFF0000u); }

// 256 blocks x 256 threads; block = 32 anchors. Merge halves, post-filter,
// recompute d22 for SOS survivors, accumulate.
__global__ __launch_bounds__(256) void merge_filter(
    const float* __restrict__ parts, const float4* __restrict__ jAg,
    const float2* __restrict__ jBg, const float* __restrict__ posg,
    const float* __restrict__ visg, const unsigned short* __restrict__ wdb,
    float* __restrict__ accum) {
  __shared__ int sJ[256];
  __shared__ float sD11[256], sD22[256], sFos[32], sVis[32], sN2[32];
  __shared__ float red[4];
  const int tid = threadIdx.x;
  const int a0 = blockIdx.x * 32;

  if (tid < 32) {
    const int a = a0 + tid;
    const int base = a & ~(NPTS - 1);
    float fD[6], fDt[6], fS[10];
    const float* P0 = parts + a;
    const float* P1 = parts + (size_t)24 * 8192 + a;
#pragma unroll
    for (int k = 0; k < 6; ++k) { fD[k] = P0[(size_t)k * 8192]; fDt[k] = P0[(size_t)(6 + k) * 8192]; }
#pragma unroll
    for (int k = 0; k < 10; ++k) fS[k] = P0[(size_t)(12 + k) * 8192];
#pragma unroll
    for (int k = 0; k < 6; ++k) {
      float v = P1[(size_t)k * 8192]; if (v > fD[5]) ins6d(v, fD);
      float w = P1[(size_t)(6 + k) * 8192]; if (w > fDt[5]) ins6d(w, fDt);
    }
#pragma unroll
    for (int k = 0; k < 10; ++k) {
      float v = P1[(size_t)(12 + k) * 8192]; if (v > fS[9]) ins10d(v, fS);
    }

    const float4 own = jAg[a];
    const float2 nb = jBg[a];
    const float pv = posg[a], vv = visg[a];
    float t1s = 0.0f, t2s = 0.0f;
    int got = 0;
#pragma unroll
    for (int k = 0; k < 6; ++k) {
      int j = (int)(__float_as_uint(fD[k]) & 0xFFFu);
      float4 jc = jAg[base + j];
      float dz = own.z - jc.z, dw = own.w - jc.w;
      if (got < 4 && dz * dz + dw * dw > 256.0f) {
        float d2 = nb.x - fD[k];
        t1s += fmaxf(1.0f + pv - sqrtf(fmaxf(d2, 1e-12f)), 0.0f);
        got++;
      }
    }
    got = 0;
#pragma unroll
    for (int k = 0; k < 6; ++k) {
      int j = (int)(__float_as_uint(fDt[k]) & 0xFFFu);
      float4 jc = jAg[base + j];
      float dz = own.z - jc.z, dw = own.w - jc.w;
      if (got < 4 && dz * dz + dw * dw > 256.0f) {
        float d2 = nb.y - fDt[k];
        t2s += fmaxf(1.0f + pv - sqrtf(fmaxf(d2, 1e-12f)), 0.0f);
        got++;
      }
    }
    int m = 0;
#pragma unroll
    for (int k = 0; k < 10; ++k) {
      int j = (int)(__float_as_uint(fS[k]) & 0xFFFu);
      float4 jc = jAg[base + j];
      float ay = own.x - jc.x, ax = own.y - jc.y;
      float wz = own.z - jc.z, ww = own.w - jc.w;
      if (m < 8 && ay * ay + ax * ax > 256.0f && wz * wz + ww * ww > 256.0f) {
        sJ[tid * 8 + m] = base + j;
        sD11[tid * 8 + m] = sqrtf(fmaxf(nb.x - fS[k], 1e-12f));
        m++;
      }
    }
    for (int k = m; k < 8; ++k) sJ[tid * 8 + k] = -1;
    sFos[tid] = vv * 0.125f * (t1s + t2s);
    sVis[tid] = vv;
    sN2[tid] = nb.y;
  }
  __syncthreads();

  // d22 for survivors: 256 slots, one thread each
  {
    const int slot = tid;
    const int al = slot >> 3;
    const int j = sJ[slot];
    float d22 = 0.0f;
    if (j >= 0) {
      const uint4* pi = (const uint4*)(wdb + (size_t)(a0 + al) * CDIM);
      const uint4* pj = (const uint4*)(wdb + (size_t)j * CDIM);
      float dot = 0.0f;
#pragma unroll
      for (int q = 0; q < 16; ++q) {
        uint4 ui = pi[q], uj = pj[q];
        dot = fmaf(bflo(ui.x), bflo(uj.x), dot); dot = fmaf(bfhi(ui.x), bfhi(uj.x), dot);
        dot = fmaf(bflo(ui.y), bflo(uj.y), dot); dot = fmaf(bfhi(ui.y), bfhi(uj.y), dot);
        dot = fmaf(bflo(ui.z), bflo(uj.z), dot); dot = fmaf(bfhi(ui.z), bfhi(uj.z), dot);
        dot = fmaf(bflo(ui.w), bflo(uj.w), dot); dot = fmaf(bfhi(ui.w), bfhi(uj.w), dot);
      }
      d22 = sqrtf(fmaxf(sN2[al] + jBg[j].y - 2.0f * dot, 1e-12f));
    }
    sD22[slot] = d22;
  }
  __syncthreads();

  float contrib = 0.0f;
  if (tid < 32) {
    float s = 0.0f;
#pragma unroll
    for (int k = 0; k < 8; ++k) {
      if (sJ[tid * 8 + k] >= 0) {
        float d = sD11[tid * 8 + k] - sD22[tid * 8 + k];
        s = fmaf(d, d, s);
      }
    }
    contrib = sFos[tid] + sVis[tid] * sqrtf(s + 1e-12f);
  }
#pragma unroll
  for (int off = 32; off >= 1; off >>= 1) contrib += __shfl_down(contrib, off, 64);
  if ((tid & 63) == 0) red[tid >> 6] = contrib;
  __syncthreads();
  if (tid == 0) atomicAdd(&accum[0], red[0] + red[1] + red[2] + red[3]);
}

__global__ __launch_bounds__(256) void finalize_kernel(
    const float* __restrict__ vis, const float* __restrict__ acc,
    float* __restrict__ out) {
  __shared__ float red[4];
  float s = 0.0f;
  for (int i = threadIdx.x; i < 2 * NPTS; i += 256) s += vis[i];
#pragma unroll
  for (int off = 32; off >= 1; off >>= 1) s += __shfl_down(s, off, 64);
  if ((threadIdx.x & 63) == 0) red[threadIdx.x >> 6] = s;
  __syncthreads();
  if (threadIdx.x == 0) {
    float denom = red[0] + red[1] + red[2] + red[3] + 1e-8f;
    out[0] = acc[0] / denom;
  }
}

extern "C" void kernel_launch(void* const* d_in, const int* in_sizes, int n_in,
                              void* d_out, int out_size, void* d_ws, size_t ws_size,
                              hipStream_t stream) {
  (void)in_sizes; (void)n_in; (void)out_size;
  const float* kp1   = (const float*)d_in[0];
  const float* wkp1  = (const float*)d_in[1];
  const float* desc  = (const float*)d_in[2];
  const float* desc2 = (const float*)d_in[3];
  const float* homo  = (const float*)d_in[4];
  float* ws = (float*)d_ws;
  unsigned short* d1b = (unsigned short*)(ws + OFF_D1B);
  unsigned short* wdb = (unsigned short*)(ws + OFF_WDB);
  float4* jA = (float4*)(ws + OFF_JA);
  float2* jB = (float2*)(ws + OFF_JB);
  float* pos = ws + OFF_POS;
  float* vis = ws + OFF_VIS;
  float* acc = ws + OFF_ACC;
  float* parts = ws + OFF_PARTS;
  unsigned short* d2t = (unsigned short*)(ws + OFF_D2T);

  hipMemsetAsync(acc, 0, 2 * sizeof(float), stream);
  if (ws_size >= (size_t)OFF_END * 4) {
    transpose_desc2<<<600, 256, 0, stream>>>(desc2, d2t);
    prep_t<<<2048, 256, 0, stream>>>(kp1, wkp1, desc, d2t, homo,
                                     d1b, wdb, jA, jB, pos, vis);
  } else {
    prep_g<<<2048, 256, 0, stream>>>(kp1, wkp1, desc, desc2, homo,
                                     d1b, wdb, jA, jB, pos, vis);
  }
  loss_main<<<1024, 512, 0, stream>>>(d1b, wdb, jB, parts);
  merge_filter<<<256, 256, 0, stream>>>(parts, jA, jB, pos, vis, wdb, acc);
  finalize_kernel<<<1, 256, 0, stream>>>(vis, acc, (float*)d_out);
}

// Round 6
// 258.500 us; speedup vs baseline: 1.2969x; 1.0817x over previous
//
#include <hip/hip_runtime.h>
#include <math.h>

#define NPTS 4096
#define CDIM 128
#define FH 120
#define FW 160
#define PIX (FH * FW)   // 19200

typedef __attribute__((ext_vector_type(8))) short short8_t;
typedef __attribute__((ext_vector_type(4))) float float4_t;
typedef __attribute__((ext_vector_type(2))) unsigned short ushort2_t;

// workspace layout (float offsets)
#define OFF_D1B   0                    // 2*4096*128 bf16 = 524288 floats
#define OFF_WDB   524288
#define OFF_JA    1048576              // float4/pt: (ky,kx,wky,wkx)
#define OFF_JB    1081344              // float2/pt: (|d1|^2, |wd|^2)
#define OFF_POS   1097728
#define OFF_VIS   1105920
#define OFF_ACC   1114112              // acc[0]=loss sum, acc[1]=vis sum, acc[2]=block counter
#define OFF_PARTS 1114128              // 2 halves * 24 lists * 8192 anchors

__device__ __forceinline__ unsigned short f2bf(float f) {
  unsigned int u = __float_as_uint(f);
  u = (u + 0x7fffu + ((u >> 16) & 1u)) >> 16;  // RNE, no NaN in this data
  return (unsigned short)u;
}

__device__ __forceinline__ float wavesum(float v) {
#pragma unroll
  for (int off = 1; off < 64; off <<= 1) v += __shfl_xor(v, off, 64);
  return v;
}

// one wave per point; lane handles channels (2*lane, 2*lane+1); also zero-inits acc
__global__ __launch_bounds__(256) void prep_g(
    const float* __restrict__ kp1, const float* __restrict__ wkp1,
    const float* __restrict__ desc, const float* __restrict__ desc2,
    const float* __restrict__ homo,
    unsigned short* __restrict__ d1b, unsigned short* __restrict__ wdb,
    float4* __restrict__ jA, float2* __restrict__ jB,
    float* __restrict__ pos, float* __restrict__ vis, float* __restrict__ acc) {
  const int tid = threadIdx.x;
  if (blockIdx.x == 0 && tid < 4) acc[tid] = 0.0f;
  const int p = blockIdx.x * 4 + (tid >> 6);
  const int lane = tid & 63;
  const int b = p >> 12;
  const int c2 = lane * 2;

  float2 v = *(const float2*)(desc + (size_t)p * CDIM + c2);
  float ss = wavesum(v.x * v.x + v.y * v.y);
  float inv = 1.0f / (sqrtf(ss) + 1e-8f);
  float d0 = v.x * inv, d1v = v.y * inv;
  ushort2_t st; st.x = f2bf(d0); st.y = f2bf(d1v);
  *(ushort2_t*)(d1b + (size_t)p * CDIM + c2) = st;
  float n1 = ss * inv * inv;

  float y = wkp1[p * 2 + 0], x = wkp1[p * 2 + 1];
  float gy = fminf(fmaxf(y * 0.125f - 0.5f, 0.0f), (float)(FH - 1));
  float gx = fminf(fmaxf(x * 0.125f - 0.5f, 0.0f), (float)(FW - 1));
  int y0 = (int)floorf(gy); y0 = min(max(y0, 0), FH - 2);
  int x0 = (int)floorf(gx); x0 = min(max(x0, 0), FW - 2);
  float wy = gy - (float)y0, wx = gx - (float)x0;
  float w00 = (1 - wy) * (1 - wx), w01 = (1 - wy) * wx;
  float w10 = wy * (1 - wx), w11 = wy * wx;
  const float* q0 = desc2 + ((size_t)b * CDIM + c2) * PIX + y0 * FW + x0;
  const float* q1 = q0 + PIX;
  float wv0 = q0[0] * w00 + q0[1] * w01 + q0[FW] * w10 + q0[FW + 1] * w11;
  float wv1 = q1[0] * w00 + q1[1] * w01 + q1[FW] * w10 + q1[FW + 1] * w11;
  float ss2 = wavesum(wv0 * wv0 + wv1 * wv1);
  float inv2 = 1.0f / (sqrtf(ss2) + 1e-8f);
  float e0 = wv0 * inv2, e1 = wv1 * inv2;
  ushort2_t sw; sw.x = f2bf(e0); sw.y = f2bf(e1);
  *(ushort2_t*)(wdb + (size_t)p * CDIM + c2) = sw;
  float n2 = ss2 * inv2 * inv2;

  float dd0 = d0 - e0, dd1 = d1v - e1;
  float ssp = wavesum(dd0 * dd0 + dd1 * dd1);

  if (lane == 0) {
    pos[p] = sqrtf(ssp + 1e-12f);
    float ky = kp1[p * 2 + 0], kx = kp1[p * 2 + 1];
    jA[p] = make_float4(ky, kx, y, x);
    jB[p] = make_float2(n1, n2);
    const float* h = homo + b * 9;
    float t0 = h[0] * kx + h[1] * ky + h[2];
    float t1 = h[3] * kx + h[4] * ky + h[5];
    float t2 = h[6] * kx + h[7] * ky + h[8];
    float qx = t0 / (t2 + 1e-8f), qy = t1 / (t2 + 1e-8f);
    vis[p] = (qx >= 0.0f && qx < 1280.0f && qy >= 0.0f && qy < 960.0f) ? 1.0f : 0.0f;
  }
}

// ---- med3-based branchless insert into sorted-descending list: K insts ----
__device__ __forceinline__ void ins4m(float v, float* L) {
  float p0 = L[0]; L[0] = fmaxf(L[0], v);
  float p1 = L[1]; L[1] = __builtin_amdgcn_fmed3f(p0, L[1], v);
  float p2 = L[2]; L[2] = __builtin_amdgcn_fmed3f(p1, L[2], v);
  L[3] = __builtin_amdgcn_fmed3f(p2, L[3], v);
}
__device__ __forceinline__ void ins6m(float v, float* L) {
  float p0 = L[0]; L[0] = fmaxf(L[0], v);
  float p1 = L[1]; L[1] = __builtin_amdgcn_fmed3f(p0, L[1], v);
  float p2 = L[2]; L[2] = __builtin_amdgcn_fmed3f(p1, L[2], v);
  float p3 = L[3]; L[3] = __builtin_amdgcn_fmed3f(p2, L[3], v);
  float p4 = L[4]; L[4] = __builtin_amdgcn_fmed3f(p3, L[4], v);
  L[5] = __builtin_amdgcn_fmed3f(p4, L[5], v);
}
__device__ __forceinline__ void ins10m(float v, float* L) {
  float p0 = L[0]; L[0] = fmaxf(L[0], v);
  float pk = p0;
#pragma unroll
  for (int k = 1; k < 9; ++k) {
    float cur = L[k];
    L[k] = __builtin_amdgcn_fmed3f(pk, cur, v);
    pk = cur;
  }
  L[9] = __builtin_amdgcn_fmed3f(pk, L[9], v);
}

// pack j (12 bits) into low mantissa of score; float ordering preserved to ~2^-12
__device__ __forceinline__ float packkey(float s, int j) {
  return __uint_as_float((__float_as_uint(s) & 0xFFFFF000u) | (unsigned)j);
}

// 1024 blocks x 512 threads (8 waves). Block = (batch, 16 anchors, j-half).
// Wave w sweeps 256 j. Per-lane lists: top-4/4/6 via med3 chains (branchless),
// expanded to 6/6/10 at merge. Partial lists -> parts[half][list][anchor].
// launch_bounds(512,4): (512,6) makes the allocator pick 40 VGPRs and spill
// (R4: 42MB scratch WRITE). Keep min-waves at 4.
__global__ __launch_bounds__(512, 4) void loss_main(
    const unsigned short* __restrict__ d1b, const unsigned short* __restrict__ wdb,
    const float2* __restrict__ jBg, float* __restrict__ parts) {
  __shared__ float mb[8][16][24];   // ladder merge buffer

  const int tid = threadIdx.x;
  const int bid = blockIdx.x;
  const int b = bid & 1;
  const int half = (bid >> 1) & 1;
  const int g = bid >> 2;                 // 0..255
  const int i0 = g * 16;
  const int wave = tid >> 6, lane = tid & 63;
  const int c = lane & 15;                // anchor class (N)
  const int quad = lane >> 4;
  const int base = b * NPTS;

  // B fragments: the 16 anchors' descriptors, resident for the whole sweep
  short8_t Bd[4], Bw[4];
  {
    const unsigned short* pa = d1b + (size_t)(base + i0 + c) * CDIM + quad * 8;
    const unsigned short* pw = wdb + (size_t)(base + i0 + c) * CDIM + quad * 8;
#pragma unroll
    for (int kc = 0; kc < 4; ++kc) {
      Bd[kc] = *(const short8_t*)(pa + kc * 32);
      Bw[kc] = *(const short8_t*)(pw + kc * 32);
    }
  }

  float fD[4], fDt[4], fS[6];
#pragma unroll
  for (int k = 0; k < 4; ++k) { fD[k] = -1e30f; fDt[k] = -1e30f; }
#pragma unroll
  for (int k = 0; k < 6; ++k) fS[k] = -1e30f;

  const int jbase0 = (half << 11) | (wave << 8);
  for (int t = 0; t < 16; ++t) {
    const int j0 = jbase0 + (t << 4);
    const unsigned short* pj1 = d1b + (size_t)(base + j0 + c) * CDIM + quad * 8;
    const unsigned short* pj2 = wdb + (size_t)(base + j0 + c) * CDIM + quad * 8;
    short8_t Ad[4], Aw[4];
#pragma unroll
    for (int kc = 0; kc < 4; ++kc) {
      Ad[kc] = *(const short8_t*)(pj1 + kc * 32);
      Aw[kc] = *(const short8_t*)(pj2 + kc * 32);
    }
    const float4 jn01 = *(const float4*)(jBg + base + j0 + (quad << 2));
    const float4 jn23 = *(const float4*)(jBg + base + j0 + (quad << 2) + 2);
    const float nj1[4] = {jn01.x, jn01.z, jn23.x, jn23.z};
    const float nj2[4] = {jn01.y, jn01.w, jn23.y, jn23.w};

    float4_t aD = {0, 0, 0, 0}, aDt = {0, 0, 0, 0}, a11 = {0, 0, 0, 0};
#pragma unroll
    for (int kc = 0; kc < 4; ++kc) {
      aD  = __builtin_amdgcn_mfma_f32_16x16x32_bf16(Aw[kc], Bd[kc], aD,  0, 0, 0);  // d1_i·wd_j
      aDt = __builtin_amdgcn_mfma_f32_16x16x32_bf16(Ad[kc], Bw[kc], aDt, 0, 0, 0);  // wd_i·d1_j
      a11 = __builtin_amdgcn_mfma_f32_16x16x32_bf16(Ad[kc], Bd[kc], a11, 0, 0, 0);  // d1_i·d1_j
    }

#pragma unroll
    for (int reg = 0; reg < 4; ++reg) {
      const int jj = j0 + (quad << 2) + reg;
      ins4m(packkey(fmaf(2.0f, aD[reg],  -nj2[reg]), jj), fD);
      ins4m(packkey(fmaf(2.0f, aDt[reg], -nj1[reg]), jj), fDt);
      ins6m(packkey(fmaf(2.0f, a11[reg], -nj1[reg]), jj), fS);
    }
  }

  // expand to merge sizes 6/6/10
  float eD[6], eDt[6], eS[10];
#pragma unroll
  for (int k = 0; k < 4; ++k) { eD[k] = fD[k]; eDt[k] = fDt[k]; }
  eD[4] = eD[5] = eDt[4] = eDt[5] = -1e30f;
#pragma unroll
  for (int k = 0; k < 6; ++k) eS[k] = fS[k];
  eS[6] = eS[7] = eS[8] = eS[9] = -1e30f;

  // merge the 4 quads (same anchor class) via shfl butterfly (snapshot first)
  {
    float tmp[10];
#pragma unroll
    for (int off = 16; off <= 32; off <<= 1) {
#pragma unroll
      for (int k = 0; k < 6; ++k) tmp[k] = eD[k];
#pragma unroll
      for (int k = 0; k < 6; ++k) ins6m(__shfl_xor(tmp[k], off, 64), eD);
#pragma unroll
      for (int k = 0; k < 6; ++k) tmp[k] = eDt[k];
#pragma unroll
      for (int k = 0; k < 6; ++k) ins6m(__shfl_xor(tmp[k], off, 64), eDt);
#pragma unroll
      for (int k = 0; k < 10; ++k) tmp[k] = eS[k];
#pragma unroll
      for (int k = 0; k < 10; ++k) ins10m(__shfl_xor(tmp[k], off, 64), eS);
    }
  }

  // ladder merge across 8 waves
#pragma unroll
  for (int h2 = 4; h2 >= 1; h2 >>= 1) {
    if (wave >= h2 && wave < 2 * h2 && lane < 16) {
      float* m = &mb[wave][lane][0];
#pragma unroll
      for (int k = 0; k < 6; ++k) { m[k] = eD[k]; m[6 + k] = eDt[k]; }
#pragma unroll
      for (int k = 0; k < 10; ++k) m[12 + k] = eS[k];
    }
    __syncthreads();
    if (wave < h2 && lane < 16) {
      const float* m = &mb[wave + h2][lane][0];
#pragma unroll
      for (int k = 0; k < 6; ++k) ins6m(m[k], eD);
#pragma unroll
      for (int k = 0; k < 6; ++k) ins6m(m[6 + k], eDt);
#pragma unroll
      for (int k = 0; k < 10; ++k) ins10m(m[12 + k], eS);
    }
  }

  if (wave == 0 && lane < 16) {
    float* P = parts + (size_t)(half * 24) * 8192 + (base + i0 + lane);
#pragma unroll
    for (int k = 0; k < 6; ++k) {
      P[(size_t)k * 8192] = eD[k];
      P[(size_t)(6 + k) * 8192] = eDt[k];
    }
#pragma unroll
    for (int k = 0; k < 10; ++k) P[(size_t)(12 + k) * 8192] = eS[k];
  }
}

__device__ __forceinline__ float bflo(unsigned int u) { return __uint_as_float(u << 16); }
__device__ __forceinline__ float bfhi(unsigned int u) { return __uint_as_float(u & 0xFFFF0000u); }

// 256 blocks x 256 threads; block = 32 anchors. Merge halves, post-filter,
// recompute d22 for SOS survivors, accumulate; last block writes the output.
__global__ __launch_bounds__(256) void merge_filter(
    const float* __restrict__ parts, const float4* __restrict__ jAg,
    const float2* __restrict__ jBg, const float* __restrict__ posg,
    const float* __restrict__ visg, const unsigned short* __restrict__ wdb,
    float* __restrict__ accum, float* __restrict__ out) {
  __shared__ int sJ[256];
  __shared__ float sD11[256], sD22[256], sFos[32], sVis[32], sN2[32];
  const int tid = threadIdx.x;
  const int a0 = blockIdx.x * 32;

  if (tid < 32) {
    const int a = a0 + tid;
    const int base = a & ~(NPTS - 1);
    float fD[6], fDt[6], fS[10];
    const float* P0 = parts + a;
    const float* P1 = parts + (size_t)24 * 8192 + a;
#pragma unroll
    for (int k = 0; k < 6; ++k) { fD[k] = P0[(size_t)k * 8192]; fDt[k] = P0[(size_t)(6 + k) * 8192]; }
#pragma unroll
    for (int k = 0; k < 10; ++k) fS[k] = P0[(size_t)(12 + k) * 8192];
#pragma unroll
    for (int k = 0; k < 6; ++k) {
      ins6m(P1[(size_t)k * 8192], fD);
      ins6m(P1[(size_t)(6 + k) * 8192], fDt);
    }
#pragma unroll
    for (int k = 0; k < 10; ++k) ins10m(P1[(size_t)(12 + k) * 8192], fS);

    const float4 own = jAg[a];
    const float2 nb = jBg[a];
    const float pv = posg[a], vv = visg[a];
    float t1s = 0.0f, t2s = 0.0f;
    int got = 0;
#pragma unroll
    for (int k = 0; k < 6; ++k) {
      int j = (int)(__float_as_uint(fD[k]) & 0xFFFu);
      float4 jc = jAg[base + j];
      float dz = own.z - jc.z, dw = own.w - jc.w;
      if (got < 4 && dz * dz + dw * dw > 256.0f) {
        float d2 = nb.x - fD[k];
        t1s += fmaxf(1.0f + pv - sqrtf(fmaxf(d2, 1e-12f)), 0.0f);
        got++;
      }
    }
    got = 0;
#pragma unroll
    for (int k = 0; k < 6; ++k) {
      int j = (int)(__float_as_uint(fDt[k]) & 0xFFFu);
      float4 jc = jAg[base + j];
      float dz = own.z - jc.z, dw = own.w - jc.w;
      if (got < 4 && dz * dz + dw * dw > 256.0f) {
        float d2 = nb.y - fDt[k];
        t2s += fmaxf(1.0f + pv - sqrtf(fmaxf(d2, 1e-12f)), 0.0f);
        got++;
      }
    }
    int m = 0;
#pragma unroll
    for (int k = 0; k < 10; ++k) {
      int j = (int)(__float_as_uint(fS[k]) & 0xFFFu);
      float4 jc = jAg[base + j];
      float ay = own.x - jc.x, ax = own.y - jc.y;
      float wz = own.z - jc.z, ww = own.w - jc.w;
      if (m < 8 && ay * ay + ax * ax > 256.0f && wz * wz + ww * ww > 256.0f) {
        sJ[tid * 8 + m] = base + j;
        sD11[tid * 8 + m] = sqrtf(fmaxf(nb.x - fS[k], 1e-12f));
        m++;
      }
    }
    for (int k = m; k < 8; ++k) sJ[tid * 8 + k] = -1;
    sFos[tid] = vv * 0.125f * (t1s + t2s);
    sVis[tid] = vv;
    sN2[tid] = nb.y;
  }
  __syncthreads();

  // d22 for survivors: 256 slots, one thread each
  {
    const int slot = tid;
    const int al = slot >> 3;
    const int j = sJ[slot];
    float d22 = 0.0f;
    if (j >= 0) {
      const uint4* pi = (const uint4*)(wdb + (size_t)(a0 + al) * CDIM);
      const uint4* pj = (const uint4*)(wdb + (size_t)j * CDIM);
      float dot = 0.0f;
#pragma unroll
      for (int q = 0; q < 16; ++q) {
        uint4 ui = pi[q], uj = pj[q];
        dot = fmaf(bflo(ui.x), bflo(uj.x), dot); dot = fmaf(bfhi(ui.x), bfhi(uj.x), dot);
        dot = fmaf(bflo(ui.y), bflo(uj.y), dot); dot = fmaf(bfhi(ui.y), bfhi(uj.y), dot);
        dot = fmaf(bflo(ui.z), bflo(uj.z), dot); dot = fmaf(bfhi(ui.z), bfhi(uj.z), dot);
        dot = fmaf(bflo(ui.w), bflo(uj.w), dot); dot = fmaf(bfhi(ui.w), bfhi(uj.w), dot);
      }
      d22 = sqrtf(fmaxf(sN2[al] + jBg[j].y - 2.0f * dot, 1e-12f));
    }
    sD22[slot] = d22;
  }
  __syncthreads();

  float contrib = 0.0f, vsum = 0.0f;
  if (tid < 32) {
    float s = 0.0f;
#pragma unroll
    for (int k = 0; k < 8; ++k) {
      if (sJ[tid * 8 + k] >= 0) {
        float d = sD11[tid * 8 + k] - sD22[tid * 8 + k];
        s = fmaf(d, d, s);
      }
    }
    contrib = sFos[tid] + sVis[tid] * sqrtf(s + 1e-12f);
    vsum = sVis[tid];
  }
  if (tid < 64) {
#pragma unroll
    for (int off = 32; off >= 1; off >>= 1) {
      contrib += __shfl_down(contrib, off, 64);
      vsum += __shfl_down(vsum, off, 64);
    }
    if (tid == 0) {
      atomicAdd(&accum[0], contrib);
      atomicAdd(&accum[1], vsum);
      __threadfence();
      float old = atomicAdd(&accum[2], 1.0f);
      if (old == 255.0f) {   // last of 256 blocks: finalize
        float t = atomicAdd(&accum[0], 0.0f);
        float v = atomicAdd(&accum[1], 0.0f);
        out[0] = t / (v + 1e-8f);
      }
    }
  }
}

extern "C" void kernel_launch(void* const* d_in, const int* in_sizes, int n_in,
                              void* d_out, int out_size, void* d_ws, size_t ws_size,
                              hipStream_t stream) {
  (void)in_sizes; (void)n_in; (void)out_size; (void)ws_size;
  const float* kp1   = (const float*)d_in[0];
  const float* wkp1  = (const float*)d_in[1];
  const float* desc  = (const float*)d_in[2];
  const float* desc2 = (const float*)d_in[3];
  const float* homo  = (const float*)d_in[4];
  float* ws = (float*)d_ws;
  unsigned short* d1b = (unsigned short*)(ws + OFF_D1B);
  unsigned short* wdb = (unsigned short*)(ws + OFF_WDB);
  float4* jA = (float4*)(ws + OFF_JA);
  float2* jB = (float2*)(ws + OFF_JB);
  float* pos = ws + OFF_POS;
  float* vis = ws + OFF_VIS;
  float* acc = ws + OFF_ACC;
  float* parts = ws + OFF_PARTS;

  prep_g<<<2048, 256, 0, stream>>>(kp1, wkp1, desc, desc2, homo,
                                   d1b, wdb, jA, jB, pos, vis, acc);
  loss_main<<<1024, 512, 0, stream>>>(d1b, wdb, jB, parts);
  merge_filter<<<256, 256, 0, stream>>>(parts, jA, jB, pos, vis, wdb, acc,
                                        (float*)d_out);
}

// Round 7
// 187.737 us; speedup vs baseline: 1.7858x; 1.3769x over previous
//
#include <hip/hip_runtime.h>
#include <math.h>

#define NPTS 4096
#define CDIM 128
#define FH 120
#define FW 160
#define PIX (FH * FW)   // 19200

typedef __attribute__((ext_vector_type(8))) short short8_t;
typedef __attribute__((ext_vector_type(4))) float float4_t;
typedef __attribute__((ext_vector_type(2))) unsigned short ushort2_t;

// workspace layout (float offsets)
// frag stream: [b][tile(256)][set(2)][kc(4)][lane(64)][8 bf16] = 4MB
#define OFF_FRAG  0
#define OFF_WDB   1048576              // wd row layout (for d22 recompute): 2MB
#define OFF_JA    1572864              // float4/pt: (ky,kx,wky,wkx)
#define OFF_JB    1605632              // float2/pt: (|d1|^2, |wd|^2)
#define OFF_POS   1622016
#define OFF_VIS   1630208
#define OFF_ACC   1638400              // [0]=loss, [1]=vis, [2]=block counter
#define OFF_PARTS 1638416              // 4 quarters * 24 lists * 8192 anchors

__device__ __forceinline__ unsigned short f2bf(float f) {
  unsigned int u = __float_as_uint(f);
  u = (u + 0x7fffu + ((u >> 16) & 1u)) >> 16;  // RNE, no NaN in this data
  return (unsigned short)u;
}

__device__ __forceinline__ float wavesum(float v) {
#pragma unroll
  for (int off = 1; off < 64; off <<= 1) v += __shfl_xor(v, off, 64);
  return v;
}

// one wave per point; lane handles channels (2*lane, 2*lane+1).
// Writes descriptors directly in MFMA fragment order (frag stream) so the
// main kernel's loads are contiguous 1KB-per-instruction.
__global__ __launch_bounds__(256) void prep_g(
    const float* __restrict__ kp1, const float* __restrict__ wkp1,
    const float* __restrict__ desc, const float* __restrict__ desc2,
    const float* __restrict__ homo,
    unsigned short* __restrict__ frag, unsigned short* __restrict__ wdb,
    float4* __restrict__ jA, float2* __restrict__ jB,
    float* __restrict__ pos, float* __restrict__ vis, float* __restrict__ acc) {
  const int tid = threadIdx.x;
  if (blockIdx.x == 0 && tid < 4) acc[tid] = 0.0f;
  const int p = blockIdx.x * 4 + (tid >> 6);
  const int lane = tid & 63;
  const int b = p >> 12;
  const int c2 = lane * 2;

  float2 v = *(const float2*)(desc + (size_t)p * CDIM + c2);
  float ss = wavesum(v.x * v.x + v.y * v.y);
  float inv = 1.0f / (sqrtf(ss) + 1e-8f);
  float d0 = v.x * inv, d1v = v.y * inv;
  float n1 = ss * inv * inv;

  float y = wkp1[p * 2 + 0], x = wkp1[p * 2 + 1];
  float gy = fminf(fmaxf(y * 0.125f - 0.5f, 0.0f), (float)(FH - 1));
  float gx = fminf(fmaxf(x * 0.125f - 0.5f, 0.0f), (float)(FW - 1));
  int y0 = (int)floorf(gy); y0 = min(max(y0, 0), FH - 2);
  int x0 = (int)floorf(gx); x0 = min(max(x0, 0), FW - 2);
  float wy = gy - (float)y0, wx = gx - (float)x0;
  float w00 = (1 - wy) * (1 - wx), w01 = (1 - wy) * wx;
  float w10 = wy * (1 - wx), w11 = wy * wx;
  const float* q0 = desc2 + ((size_t)b * CDIM + c2) * PIX + y0 * FW + x0;
  const float* q1 = q0 + PIX;
  float wv0 = q0[0] * w00 + q0[1] * w01 + q0[FW] * w10 + q0[FW + 1] * w11;
  float wv1 = q1[0] * w00 + q1[1] * w01 + q1[FW] * w10 + q1[FW + 1] * w11;
  float ss2 = wavesum(wv0 * wv0 + wv1 * wv1);
  float inv2 = 1.0f / (sqrtf(ss2) + 1e-8f);
  float e0 = wv0 * inv2, e1 = wv1 * inv2;
  float n2 = ss2 * inv2 * inv2;

  // ---- frag stream writes (MFMA order) ----
  // channel k: kc=k>>5, quad=(k>>3)&3, jj=k&7; lane's pair shares one octet
  {
    const int T = (p & (NPTS - 1)) >> 4, cRow = p & 15;
    const int kcL = lane >> 4, quadL = (lane >> 2) & 3, jjL = (lane & 3) * 2;
    const size_t off = (size_t)(quadL * 16 + cRow) * 8 + jjL;
    const size_t tb = (((size_t)b * 256 + T) * 2) * 4;   // block index, set 0
    ushort2_t st; st.x = f2bf(d0); st.y = f2bf(d1v);
    ushort2_t sw; sw.x = f2bf(e0); sw.y = f2bf(e1);
    *(ushort2_t*)(frag + (tb + kcL) * 512 + off) = st;
    *(ushort2_t*)(frag + (tb + 4 + kcL) * 512 + off) = sw;
    // row layout of wd for the d22 recompute in merge_filter
    ushort2_t swr; swr.x = f2bf(e0); swr.y = f2bf(e1);
    *(ushort2_t*)(wdb + (size_t)p * CDIM + c2) = swr;
  }

  float dd0 = d0 - e0, dd1 = d1v - e1;
  float ssp = wavesum(dd0 * dd0 + dd1 * dd1);

  if (lane == 0) {
    pos[p] = sqrtf(ssp + 1e-12f);
    float ky = kp1[p * 2 + 0], kx = kp1[p * 2 + 1];
    jA[p] = make_float4(ky, kx, y, x);
    jB[p] = make_float2(n1, n2);
    const float* h = homo + b * 9;
    float t0 = h[0] * kx + h[1] * ky + h[2];
    float t1 = h[3] * kx + h[4] * ky + h[5];
    float t2 = h[6] * kx + h[7] * ky + h[8];
    float qx = t0 / (t2 + 1e-8f), qy = t1 / (t2 + 1e-8f);
    vis[p] = (qx >= 0.0f && qx < 1280.0f && qy >= 0.0f && qy < 960.0f) ? 1.0f : 0.0f;
  }
}

// ---- med3-based branchless insert into sorted-descending list ----
__device__ __forceinline__ void ins4m(float v, float* L) {
  float p0 = L[0]; L[0] = fmaxf(L[0], v);
  float p1 = L[1]; L[1] = __builtin_amdgcn_fmed3f(p0, L[1], v);
  float p2 = L[2]; L[2] = __builtin_amdgcn_fmed3f(p1, L[2], v);
  L[3] = __builtin_amdgcn_fmed3f(p2, L[3], v);
}
__device__ __forceinline__ void ins6m(float v, float* L) {
  float p0 = L[0]; L[0] = fmaxf(L[0], v);
  float p1 = L[1]; L[1] = __builtin_amdgcn_fmed3f(p0, L[1], v);
  float p2 = L[2]; L[2] = __builtin_amdgcn_fmed3f(p1, L[2], v);
  float p3 = L[3]; L[3] = __builtin_amdgcn_fmed3f(p2, L[3], v);
  float p4 = L[4]; L[4] = __builtin_amdgcn_fmed3f(p3, L[4], v);
  L[5] = __builtin_amdgcn_fmed3f(p4, L[5], v);
}
__device__ __forceinline__ void ins10m(float v, float* L) {
  float p0 = L[0]; L[0] = fmaxf(L[0], v);
  float pk = p0;
#pragma unroll
  for (int k = 1; k < 9; ++k) {
    float cur = L[k];
    L[k] = __builtin_amdgcn_fmed3f(pk, cur, v);
    pk = cur;
  }
  L[9] = __builtin_amdgcn_fmed3f(pk, L[9], v);
}

// pack j (12 bits) into low mantissa of score
__device__ __forceinline__ float packkey(float s, int j) {
  return __uint_as_float((__float_as_uint(s) & 0xFFFFF000u) | (unsigned)j);
}

#define TILE_COMPUTE(AD, AW, NA, NB, J0) do {                                   \
  float4_t aD = {0,0,0,0}, aDt = {0,0,0,0}, a11 = {0,0,0,0};                    \
  _Pragma("unroll")                                                             \
  for (int kc = 0; kc < 4; ++kc) {                                              \
    aD  = __builtin_amdgcn_mfma_f32_16x16x32_bf16(AW[kc], Bd[kc], aD,  0,0,0);  \
    aDt = __builtin_amdgcn_mfma_f32_16x16x32_bf16(AD[kc], Bw[kc], aDt, 0,0,0);  \
    a11 = __builtin_amdgcn_mfma_f32_16x16x32_bf16(AD[kc], Bd[kc], a11, 0,0,0);  \
  }                                                                             \
  const float nj1[4] = {NA.x, NA.z, NB.x, NB.z};                                \
  const float nj2[4] = {NA.y, NA.w, NB.y, NB.w};                                \
  _Pragma("unroll")                                                             \
  for (int reg = 0; reg < 4; ++reg) {                                           \
    const int jj = (J0) + (quad << 2) + reg;                                    \
    ins4m(packkey(fmaf(2.0f, aD[reg],  -nj2[reg]), jj), fD);                    \
    ins4m(packkey(fmaf(2.0f, aDt[reg], -nj1[reg]), jj), fDt);                   \
    ins6m(packkey(fmaf(2.0f, a11[reg], -nj1[reg]), jj), fS);                    \
  }                                                                             \
} while (0)

// 2048 blocks x 256 threads (4 waves). Block = (batch, 16 anchors, j-quarter).
// Wave w sweeps 256 j (16 tiles) with a 2-stage ping-pong pipeline; all loads
// are contiguous 1KB-per-instruction from the frag stream.
__global__ __launch_bounds__(256, 3) void loss_main(
    const unsigned short* __restrict__ frag,
    const float2* __restrict__ jBg, float* __restrict__ parts) {
  __shared__ float mb[4][16][24];

  const int tid = threadIdx.x;
  const int bid = blockIdx.x;
  const int b = bid & 1;
  const int q = (bid >> 1) & 3;
  const int g = bid >> 3;                 // 0..255
  const int i0 = g * 16;
  const int wave = tid >> 6, lane = tid & 63;
  const int c = lane & 15, quad = lane >> 4;
  const int base = b * NPTS;

  // B fragments: anchors = tile g of this batch
  short8_t Bd[4], Bw[4];
  {
    const unsigned short* fb = frag + ((((size_t)b * 256 + g) * 2) * 4) * 512 + (size_t)lane * 8;
#pragma unroll
    for (int kc = 0; kc < 4; ++kc) {
      Bd[kc] = *(const short8_t*)(fb + kc * 512);
      Bw[kc] = *(const short8_t*)(fb + (4 + kc) * 512);
    }
  }

  float fD[4], fDt[4], fS[6];
#pragma unroll
  for (int k = 0; k < 4; ++k) { fD[k] = -1e30f; fDt[k] = -1e30f; }
#pragma unroll
  for (int k = 0; k < 6; ++k) fS[k] = -1e30f;

  const int jstart = (q << 10) | (wave << 8);
  const unsigned short* fa = frag + (((size_t)b * 256 + (jstart >> 4)) * 8) * 512 + (size_t)lane * 8;
  const float2* jbb = jBg + base;

  short8_t A0d[4], A0w[4], A1d[4], A1w[4];
#pragma unroll
  for (int kc = 0; kc < 4; ++kc) {
    A0d[kc] = *(const short8_t*)(fa + kc * 512);
    A0w[kc] = *(const short8_t*)(fa + (4 + kc) * 512);
  }
  float4 n0a = *(const float4*)(jbb + jstart + (quad << 2));
  float4 n0b = *(const float4*)(jbb + jstart + (quad << 2) + 2);
  float4 n1a, n1b;

  for (int t = 0; t < 16; t += 2) {
    const unsigned short* f1 = fa + 4096;            // tile t+1
#pragma unroll
    for (int kc = 0; kc < 4; ++kc) {
      A1d[kc] = *(const short8_t*)(f1 + kc * 512);
      A1w[kc] = *(const short8_t*)(f1 + (4 + kc) * 512);
    }
    {
      const int j1 = jstart + ((t + 1) << 4);
      n1a = *(const float4*)(jbb + j1 + (quad << 2));
      n1b = *(const float4*)(jbb + j1 + (quad << 2) + 2);
    }
    TILE_COMPUTE(A0d, A0w, n0a, n0b, jstart + (t << 4));
    const unsigned short* f2 = fa + ((t + 2 < 16) ? 8192 : 0);   // tile t+2 (wrap harmless)
#pragma unroll
    for (int kc = 0; kc < 4; ++kc) {
      A0d[kc] = *(const short8_t*)(f2 + kc * 512);
      A0w[kc] = *(const short8_t*)(f2 + (4 + kc) * 512);
    }
    {
      const int j2 = jstart + (((t + 2) & 15) << 4);
      n0a = *(const float4*)(jbb + j2 + (quad << 2));
      n0b = *(const float4*)(jbb + j2 + (quad << 2) + 2);
    }
    TILE_COMPUTE(A1d, A1w, n1a, n1b, jstart + ((t + 1) << 4));
    fa += 8192;
  }

  // expand to merge sizes 6/6/10
  float eD[6], eDt[6], eS[10];
#pragma unroll
  for (int k = 0; k < 4; ++k) { eD[k] = fD[k]; eDt[k] = fDt[k]; }
  eD[4] = eD[5] = eDt[4] = eDt[5] = -1e30f;
#pragma unroll
  for (int k = 0; k < 6; ++k) eS[k] = fS[k];
  eS[6] = eS[7] = eS[8] = eS[9] = -1e30f;

  // merge the 4 quads (same anchor class) via shfl butterfly (snapshot first)
  {
    float tmp[10];
#pragma unroll
    for (int off = 16; off <= 32; off <<= 1) {
#pragma unroll
      for (int k = 0; k < 6; ++k) tmp[k] = eD[k];
#pragma unroll
      for (int k = 0; k < 6; ++k) ins6m(__shfl_xor(tmp[k], off, 64), eD);
#pragma unroll
      for (int k = 0; k < 6; ++k) tmp[k] = eDt[k];
#pragma unroll
      for (int k = 0; k < 6; ++k) ins6m(__shfl_xor(tmp[k], off, 64), eDt);
#pragma unroll
      for (int k = 0; k < 10; ++k) tmp[k] = eS[k];
#pragma unroll
      for (int k = 0; k < 10; ++k) ins10m(__shfl_xor(tmp[k], off, 64), eS);
    }
  }

  // ladder merge across 4 waves
#pragma unroll
  for (int h2 = 2; h2 >= 1; h2 >>= 1) {
    if (wave >= h2 && wave < 2 * h2 && lane < 16) {
      float* m = &mb[wave][lane][0];
#pragma unroll
      for (int k = 0; k < 6; ++k) { m[k] = eD[k]; m[6 + k] = eDt[k]; }
#pragma unroll
      for (int k = 0; k < 10; ++k) m[12 + k] = eS[k];
    }
    __syncthreads();
    if (wave < h2 && lane < 16) {
      const float* m = &mb[wave + h2][lane][0];
#pragma unroll
      for (int k = 0; k < 6; ++k) ins6m(m[k], eD);
#pragma unroll
      for (int k = 0; k < 6; ++k) ins6m(m[6 + k], eDt);
#pragma unroll
      for (int k = 0; k < 10; ++k) ins10m(m[12 + k], eS);
    }
  }

  if (wave == 0 && lane < 16) {
    float* P = parts + (size_t)(q * 24) * 8192 + (base + i0 + lane);
#pragma unroll
    for (int k = 0; k < 6; ++k) {
      P[(size_t)k * 8192] = eD[k];
      P[(size_t)(6 + k) * 8192] = eDt[k];
    }
#pragma unroll
    for (int k = 0; k < 10; ++k) P[(size_t)(12 + k) * 8192] = eS[k];
  }
}

__device__ __forceinline__ float bflo(unsigned int u) { return __uint_as_float(u << 16); }
__device__ __forceinline__ float bfhi(unsigned int u) { return __uint_as_float(u & 0xFFFF0000u); }

// 256 blocks x 256 threads; block = 32 anchors. Merge 4 quarter-segments,
// post-filter, recompute d22 for SOS survivors, accumulate; last block finalizes.
__global__ __launch_bounds__(256) void merge_filter(
    const float* __restrict__ parts, const float4* __restrict__ jAg,
    const float2* __restrict__ jBg, const float* __restrict__ posg,
    const float* __restrict__ visg, const unsigned short* __restrict__ wdb,
    float* __restrict__ accum, float* __restrict__ out) {
  __shared__ int sJ[256];
  __shared__ float sD11[256], sD22[256], sFos[32], sVis[32], sN2[32];
  const int tid = threadIdx.x;
  const int a0 = blockIdx.x * 32;

  if (tid < 32) {
    const int a = a0 + tid;
    const int base = a & ~(NPTS - 1);
    float fD[6], fDt[6], fS[10];
    const float* P = parts + a;
#pragma unroll
    for (int k = 0; k < 6; ++k) { fD[k] = P[(size_t)k * 8192]; fDt[k] = P[(size_t)(6 + k) * 8192]; }
#pragma unroll
    for (int k = 0; k < 10; ++k) fS[k] = P[(size_t)(12 + k) * 8192];
#pragma unroll
    for (int seg = 1; seg < 4; ++seg) {
      const float* Q = P + (size_t)(seg * 24) * 8192;
#pragma unroll
      for (int k = 0; k < 6; ++k) {
        ins6m(Q[(size_t)k * 8192], fD);
        ins6m(Q[(size_t)(6 + k) * 8192], fDt);
      }
#pragma unroll
      for (int k = 0; k < 10; ++k) ins10m(Q[(size_t)(12 + k) * 8192], fS);
    }

    const float4 own = jAg[a];
    const float2 nb = jBg[a];
    const float pv = posg[a], vv = visg[a];
    float t1s = 0.0f, t2s = 0.0f;
    int got = 0;
#pragma unroll
    for (int k = 0; k < 6; ++k) {
      int j = (int)(__float_as_uint(fD[k]) & 0xFFFu);
      float4 jc = jAg[base + j];
      float dz = own.z - jc.z, dw = own.w - jc.w;
      if (got < 4 && dz * dz + dw * dw > 256.0f) {
        float d2 = nb.x - fD[k];
        t1s += fmaxf(1.0f + pv - sqrtf(fmaxf(d2, 1e-12f)), 0.0f);
        got++;
      }
    }
    got = 0;
#pragma unroll
    for (int k = 0; k < 6; ++k) {
      int j = (int)(__float_as_uint(fDt[k]) & 0xFFFu);
      float4 jc = jAg[base + j];
      float dz = own.z - jc.z, dw = own.w - jc.w;
      if (got < 4 && dz * dz + dw * dw > 256.0f) {
        float d2 = nb.y - fDt[k];
        t2s += fmaxf(1.0f + pv - sqrtf(fmaxf(d2, 1e-12f)), 0.0f);
        got++;
      }
    }
    int m = 0;
#pragma unroll
    for (int k = 0; k < 10; ++k) {
      int j = (int)(__float_as_uint(fS[k]) & 0xFFFu);
      float4 jc = jAg[base + j];
      float ay = own.x - jc.x, ax = own.y - jc.y;
      float wz = own.z - jc.z, ww = own.w - jc.w;
      if (m < 8 && ay * ay + ax * ax > 256.0f && wz * wz + ww * ww > 256.0f) {
        sJ[tid * 8 + m] = base + j;
        sD11[tid * 8 + m] = sqrtf(fmaxf(nb.x - fS[k], 1e-12f));
        m++;
      }
    }
    for (int k = m; k < 8; ++k) sJ[tid * 8 + k] = -1;
    sFos[tid] = vv * 0.125f * (t1s + t2s);
    sVis[tid] = vv;
    sN2[tid] = nb.y;
  }
  __syncthreads();

  // d22 for survivors: 256 slots, one thread each
  {
    const int slot = tid;
    const int al = slot >> 3;
    const int j = sJ[slot];
    float d22 = 0.0f;
    if (j >= 0) {
      const uint4* pi = (const uint4*)(wdb + (size_t)(a0 + al) * CDIM);
      const uint4* pj = (const uint4*)(wdb + (size_t)j * CDIM);
      float dot = 0.0f;
#pragma unroll
      for (int qq = 0; qq < 16; ++qq) {
        uint4 ui = pi[qq], uj = pj[qq];
        dot = fmaf(bflo(ui.x), bflo(uj.x), dot); dot = fmaf(bfhi(ui.x), bfhi(uj.x), dot);
        dot = fmaf(bflo(ui.y), bflo(uj.y), dot); dot = fmaf(bfhi(ui.y), bfhi(uj.y), dot);
        dot = fmaf(bflo(ui.z), bflo(uj.z), dot); dot = fmaf(bfhi(ui.z), bfhi(uj.z), dot);
        dot = fmaf(bflo(ui.w), bflo(uj.w), dot); dot = fmaf(bfhi(ui.w), bfhi(uj.w), dot);
      }
      d22 = sqrtf(fmaxf(sN2[al] + jBg[j].y - 2.0f * dot, 1e-12f));
    }
    sD22[slot] = d22;
  }
  __syncthreads();

  float contrib = 0.0f, vsum = 0.0f;
  if (tid < 32) {
    float s = 0.0f;
#pragma unroll
    for (int k = 0; k < 8; ++k) {
      if (sJ[tid * 8 + k] >= 0) {
        float d = sD11[tid * 8 + k] - sD22[tid * 8 + k];
        s = fmaf(d, d, s);
      }
    }
    contrib = sFos[tid] + sVis[tid] * sqrtf(s + 1e-12f);
    vsum = sVis[tid];
  }
  if (tid < 64) {
#pragma unroll
    for (int off = 32; off >= 1; off >>= 1) {
      contrib += __shfl_down(contrib, off, 64);
      vsum += __shfl_down(vsum, off, 64);
    }
    if (tid == 0) {
      atomicAdd(&accum[0], contrib);
      atomicAdd(&accum[1], vsum);
      __threadfence();
      float old = atomicAdd(&accum[2], 1.0f);
      if (old == 255.0f) {
        float t = atomicAdd(&accum[0], 0.0f);
        float v = atomicAdd(&accum[1], 0.0f);
        out[0] = t / (v + 1e-8f);
      }
    }
  }
}

extern "C" void kernel_launch(void* const* d_in, const int* in_sizes, int n_in,
                              void* d_out, int out_size, void* d_ws, size_t ws_size,
                              hipStream_t stream) {
  (void)in_sizes; (void)n_in; (void)out_size; (void)ws_size;
  const float* kp1   = (const float*)d_in[0];
  const float* wkp1  = (const float*)d_in[1];
  const float* desc  = (const float*)d_in[2];
  const float* desc2 = (const float*)d_in[3];
  const float* homo  = (const float*)d_in[4];
  float* ws = (float*)d_ws;
  unsigned short* frag = (unsigned short*)(ws + OFF_FRAG);
  unsigned short* wdb  = (unsigned short*)(ws + OFF_WDB);
  float4* jA = (float4*)(ws + OFF_JA);
  float2* jB = (float2*)(ws + OFF_JB);
  float* pos = ws + OFF_POS;
  float* vis = ws + OFF_VIS;
  float* acc = ws + OFF_ACC;
  float* parts = ws + OFF_PARTS;

  prep_g<<<2048, 256, 0, stream>>>(kp1, wkp1, desc, desc2, homo,
                                   frag, wdb, jA, jB, pos, vis, acc);
  loss_main<<<2048, 256, 0, stream>>>(frag, jB, parts);
  merge_filter<<<256, 256, 0, stream>>>(parts, jA, jB, pos, vis, wdb, acc,
                                        (float*)d_out);
}

// Round 8
// 169.466 us; speedup vs baseline: 1.9783x; 1.1078x over previous
//
#include <hip/hip_runtime.h>
#include <hip/hip_fp16.h>
#include <math.h>

#define NPTS 4096
#define CDIM 128
#define FH 120
#define FW 160
#define PIX (FH * FW)   // 19200

typedef __attribute__((ext_vector_type(8))) short short8_t;
typedef __attribute__((ext_vector_type(4))) float float4_t;
typedef __attribute__((ext_vector_type(2))) unsigned short ushort2_t;

// workspace layout (float offsets)
// frag stream: [b][tile(256)][set(2)][kc(4)][lane(64)][8 bf16] = 4MB
#define OFF_FRAG  0
#define OFF_WDB   1048576              // wd row layout (for d22 recompute)
#define OFF_JA    1572864              // float4/pt: (ky,kx,wky,wkx)
#define OFF_JB    1605632              // float2/pt: (|d1|^2, |wd|^2)
#define OFF_POS   1622016
#define OFF_VIS   1630208
#define OFF_ACC   1638400              // [0]=loss, [1]=vis, [2]=block counter
#define OFF_PARTS 1638416              // 2 halves * 24 lists * 8192 anchors
#define OFF_D2T   2031632              // fp16 transposed desc2
#define OFF_END   4489232

__device__ __forceinline__ unsigned short f2bf(float f) {
  unsigned int u = __float_as_uint(f);
  u = (u + 0x7fffu + ((u >> 16) & 1u)) >> 16;  // RNE, no NaN in this data
  return (unsigned short)u;
}

__device__ __forceinline__ float wavesum(float v) {
#pragma unroll
  for (int off = 1; off < 64; off <<= 1) v += __shfl_xor(v, off, 64);
  return v;
}

// ---- desc2 [b][c][pix] f32  ->  [b][pix][c] f16 ----
__global__ __launch_bounds__(256) void transpose_desc2(
    const float* __restrict__ d2, unsigned short* __restrict__ out) {
  __shared__ unsigned short tile[64][130];
  const int bp = blockIdx.x;            // 0..599
  const int b = bp / 300;
  const int p0 = (bp - b * 300) * 64;
  const int tid = threadIdx.x;
  const int grp = tid >> 6, lp = tid & 63;
#pragma unroll 4
  for (int r = 0; r < 32; ++r) {
    int c = (r << 2) | grp;
    float v = d2[((size_t)b * CDIM + c) * PIX + p0 + lp];
    tile[lp][c] = __half_as_ushort(__float2half(v));
  }
  __syncthreads();
  unsigned int* ob = (unsigned int*)(out + ((size_t)b * PIX + p0) * CDIM);
#pragma unroll
  for (int i = 0; i < 16; ++i) {
    int u = (i << 8) | tid;
    int p = u >> 6, cc = (u & 63) << 1;
    unsigned int lo = tile[p][cc], hi = tile[p][cc + 1];
    ob[u] = lo | (hi << 16);
  }
}

// shared tail of both prep variants: frag-stream + scalar writes
#define PREP_TAIL() do {                                                        \
  {                                                                             \
    const int T = (p & (NPTS - 1)) >> 4, cRow = p & 15;                         \
    const int kcL = lane >> 4, quadL = (lane >> 2) & 3, jjL = (lane & 3) * 2;   \
    const size_t off = (size_t)(quadL * 16 + cRow) * 8 + jjL;                   \
    const size_t tb = (((size_t)b * 256 + T) * 2) * 4;                          \
    ushort2_t st; st.x = f2bf(d0); st.y = f2bf(d1v);                            \
    ushort2_t sw; sw.x = f2bf(e0); sw.y = f2bf(e1);                             \
    *(ushort2_t*)(frag + (tb + kcL) * 512 + off) = st;                          \
    *(ushort2_t*)(frag + (tb + 4 + kcL) * 512 + off) = sw;                      \
    ushort2_t swr; swr.x = f2bf(e0); swr.y = f2bf(e1);                          \
    *(ushort2_t*)(wdb + (size_t)p * CDIM + c2) = swr;                           \
  }                                                                             \
  float dd0 = d0 - e0, dd1 = d1v - e1;                                          \
  float ssp = wavesum(dd0 * dd0 + dd1 * dd1);                                   \
  if (lane == 0) {                                                              \
    pos[p] = sqrtf(ssp + 1e-12f);                                               \
    float ky = kp1[p * 2 + 0], kx = kp1[p * 2 + 1];                             \
    jA[p] = make_float4(ky, kx, y, x);                                          \
    jB[p] = make_float2(n1, n2);                                                \
    const float* h = homo + b * 9;                                              \
    float t0 = h[0] * kx + h[1] * ky + h[2];                                    \
    float t1 = h[3] * kx + h[4] * ky + h[5];                                    \
    float t2 = h[6] * kx + h[7] * ky + h[8];                                    \
    float qx = t0 / (t2 + 1e-8f), qy = t1 / (t2 + 1e-8f);                       \
    vis[p] = (qx >= 0.0f && qx < 1280.0f && qy >= 0.0f && qy < 960.0f)          \
                 ? 1.0f : 0.0f;                                                 \
  }                                                                             \
} while (0)

// one wave per point; bilinear from fp16-transposed desc2 (coalesced)
__global__ __launch_bounds__(256) void prep_t(
    const float* __restrict__ kp1, const float* __restrict__ wkp1,
    const float* __restrict__ desc, const unsigned short* __restrict__ d2t,
    const float* __restrict__ homo,
    unsigned short* __restrict__ frag, unsigned short* __restrict__ wdb,
    float4* __restrict__ jA, float2* __restrict__ jB,
    float* __restrict__ pos, float* __restrict__ vis, float* __restrict__ acc) {
  const int tid = threadIdx.x;
  if (blockIdx.x == 0 && tid < 4) acc[tid] = 0.0f;
  const int p = blockIdx.x * 4 + (tid >> 6);
  const int lane = tid & 63;
  const int b = p >> 12;
  const int c2 = lane * 2;

  float2 v = *(const float2*)(desc + (size_t)p * CDIM + c2);
  float ss = wavesum(v.x * v.x + v.y * v.y);
  float inv = 1.0f / (sqrtf(ss) + 1e-8f);
  float d0 = v.x * inv, d1v = v.y * inv;
  float n1 = ss * inv * inv;

  float y = wkp1[p * 2 + 0], x = wkp1[p * 2 + 1];
  float gy = fminf(fmaxf(y * 0.125f - 0.5f, 0.0f), (float)(FH - 1));
  float gx = fminf(fmaxf(x * 0.125f - 0.5f, 0.0f), (float)(FW - 1));
  int y0 = (int)floorf(gy); y0 = min(max(y0, 0), FH - 2);
  int x0 = (int)floorf(gx); x0 = min(max(x0, 0), FW - 2);
  float wy = gy - (float)y0, wx = gx - (float)x0;
  float w00 = (1 - wy) * (1 - wx), w01 = (1 - wy) * wx;
  float w10 = wy * (1 - wx), w11 = wy * wx;
  const unsigned int* t00 = (const unsigned int*)
      (d2t + ((size_t)b * PIX + y0 * FW + x0) * CDIM) + lane;
  unsigned int u00 = t00[0], u01 = t00[64];
  unsigned int u10 = t00[FW * 64], u11 = t00[FW * 64 + 64];
  float2 f00 = __half22float2(*(const __half2*)&u00);
  float2 f01 = __half22float2(*(const __half2*)&u01);
  float2 f10 = __half22float2(*(const __half2*)&u10);
  float2 f11 = __half22float2(*(const __half2*)&u11);
  float wv0 = f00.x * w00 + f01.x * w01 + f10.x * w10 + f11.x * w11;
  float wv1 = f00.y * w00 + f01.y * w01 + f10.y * w10 + f11.y * w11;
  float ss2 = wavesum(wv0 * wv0 + wv1 * wv1);
  float inv2 = 1.0f / (sqrtf(ss2) + 1e-8f);
  float e0 = wv0 * inv2, e1 = wv1 * inv2;
  float n2 = ss2 * inv2 * inv2;

  PREP_TAIL();
}

// fallback: direct fp32 gather from desc2 (when ws too small for transpose)
__global__ __launch_bounds__(256) void prep_g(
    const float* __restrict__ kp1, const float* __restrict__ wkp1,
    const float* __restrict__ desc, const float* __restrict__ desc2,
    const float* __restrict__ homo,
    unsigned short* __restrict__ frag, unsigned short* __restrict__ wdb,
    float4* __restrict__ jA, float2* __restrict__ jB,
    float* __restrict__ pos, float* __restrict__ vis, float* __restrict__ acc) {
  const int tid = threadIdx.x;
  if (blockIdx.x == 0 && tid < 4) acc[tid] = 0.0f;
  const int p = blockIdx.x * 4 + (tid >> 6);
  const int lane = tid & 63;
  const int b = p >> 12;
  const int c2 = lane * 2;

  float2 v = *(const float2*)(desc + (size_t)p * CDIM + c2);
  float ss = wavesum(v.x * v.x + v.y * v.y);
  float inv = 1.0f / (sqrtf(ss) + 1e-8f);
  float d0 = v.x * inv, d1v = v.y * inv;
  float n1 = ss * inv * inv;

  float y = wkp1[p * 2 + 0], x = wkp1[p * 2 + 1];
  float gy = fminf(fmaxf(y * 0.125f - 0.5f, 0.0f), (float)(FH - 1));
  float gx = fminf(fmaxf(x * 0.125f - 0.5f, 0.0f), (float)(FW - 1));
  int y0 = (int)floorf(gy); y0 = min(max(y0, 0), FH - 2);
  int x0 = (int)floorf(gx); x0 = min(max(x0, 0), FW - 2);
  float wy = gy - (float)y0, wx = gx - (float)x0;
  float w00 = (1 - wy) * (1 - wx), w01 = (1 - wy) * wx;
  float w10 = wy * (1 - wx), w11 = wy * wx;
  const float* q0 = desc2 + ((size_t)b * CDIM + c2) * PIX + y0 * FW + x0;
  const float* q1 = q0 + PIX;
  float wv0 = q0[0] * w00 + q0[1] * w01 + q0[FW] * w10 + q0[FW + 1] * w11;
  float wv1 = q1[0] * w00 + q1[1] * w01 + q1[FW] * w10 + q1[FW + 1] * w11;
  float ss2 = wavesum(wv0 * wv0 + wv1 * wv1);
  float inv2 = 1.0f / (sqrtf(ss2) + 1e-8f);
  float e0 = wv0 * inv2, e1 = wv1 * inv2;
  float n2 = ss2 * inv2 * inv2;

  PREP_TAIL();
}

// ---- med3-based branchless insert into sorted-descending list ----
__device__ __forceinline__ void ins4m(float v, float* L) {
  float p0 = L[0]; L[0] = fmaxf(L[0], v);
  float p1 = L[1]; L[1] = __builtin_amdgcn_fmed3f(p0, L[1], v);
  float p2 = L[2]; L[2] = __builtin_amdgcn_fmed3f(p1, L[2], v);
  L[3] = __builtin_amdgcn_fmed3f(p2, L[3], v);
}
__device__ __forceinline__ void ins6m(float v, float* L) {
  float p0 = L[0]; L[0] = fmaxf(L[0], v);
  float p1 = L[1]; L[1] = __builtin_amdgcn_fmed3f(p0, L[1], v);
  float p2 = L[2]; L[2] = __builtin_amdgcn_fmed3f(p1, L[2], v);
  float p3 = L[3]; L[3] = __builtin_amdgcn_fmed3f(p2, L[3], v);
  float p4 = L[4]; L[4] = __builtin_amdgcn_fmed3f(p3, L[4], v);
  L[5] = __builtin_amdgcn_fmed3f(p4, L[5], v);
}
__device__ __forceinline__ void ins10m(float v, float* L) {
  float p0 = L[0]; L[0] = fmaxf(L[0], v);
  float pk = p0;
#pragma unroll
  for (int k = 1; k < 9; ++k) {
    float cur = L[k];
    L[k] = __builtin_amdgcn_fmed3f(pk, cur, v);
    pk = cur;
  }
  L[9] = __builtin_amdgcn_fmed3f(pk, L[9], v);
}

// pack j (12 bits) into low mantissa of score
__device__ __forceinline__ float packkey(float s, int j) {
  return __uint_as_float((__float_as_uint(s) & 0xFFFFF000u) | (unsigned)j);
}

#define TILE_COMPUTE(AD, AW, NA, NB, J0) do {                                   \
  float4_t aD = {0,0,0,0}, aDt = {0,0,0,0}, a11 = {0,0,0,0};                    \
  _Pragma("unroll")                                                             \
  for (int kc = 0; kc < 4; ++kc) {                                              \
    aD  = __builtin_amdgcn_mfma_f32_16x16x32_bf16(AW[kc], Bd[kc], aD,  0,0,0);  \
    aDt = __builtin_amdgcn_mfma_f32_16x16x32_bf16(AD[kc], Bw[kc], aDt, 0,0,0);  \
    a11 = __builtin_amdgcn_mfma_f32_16x16x32_bf16(AD[kc], Bd[kc], a11, 0,0,0);  \
  }                                                                             \
  const float nj1[4] = {NA.x, NA.z, NB.x, NB.z};                                \
  const float nj2[4] = {NA.y, NA.w, NB.y, NB.w};                                \
  _Pragma("unroll")                                                             \
  for (int reg = 0; reg < 4; ++reg) {                                           \
    const int jj = (J0) + (quad << 2) + reg;                                    \
    ins4m(packkey(fmaf(2.0f, aD[reg],  -nj2[reg]), jj), fD);                    \
    ins4m(packkey(fmaf(2.0f, aDt[reg], -nj1[reg]), jj), fDt);                   \
    ins6m(packkey(fmaf(2.0f, a11[reg], -nj1[reg]), jj), fS);                    \
  }                                                                             \
} while (0)

// 1024 blocks x 256 threads (4 waves). Block = (batch, 16 anchors, j-half).
// Wave w sweeps 512 j (32 tiles) with the 2-stage ping-pong pipeline; the
// merge epilogue amortizes over 2x the sweep of R7.
__global__ __launch_bounds__(256, 3) void loss_main(
    const unsigned short* __restrict__ frag,
    const float2* __restrict__ jBg, float* __restrict__ parts) {
  __shared__ float mb[4][16][24];

  const int tid = threadIdx.x;
  const int bid = blockIdx.x;
  const int b = bid & 1;
  const int half = (bid >> 1) & 1;
  const int g = bid >> 2;                 // 0..255
  const int i0 = g * 16;
  const int wave = tid >> 6, lane = tid & 63;
  const int c = lane & 15, quad = lane >> 4;
  const int base = b * NPTS;

  // B fragments: anchors = tile g of this batch
  short8_t Bd[4], Bw[4];
  {
    const unsigned short* fb = frag + ((((size_t)b * 256 + g) * 2) * 4) * 512 + (size_t)lane * 8;
#pragma unroll
    for (int kc = 0; kc < 4; ++kc) {
      Bd[kc] = *(const short8_t*)(fb + kc * 512);
      Bw[kc] = *(const short8_t*)(fb + (4 + kc) * 512);
    }
  }

  float fD[4], fDt[4], fS[6];
#pragma unroll
  for (int k = 0; k < 4; ++k) { fD[k] = -1e30f; fDt[k] = -1e30f; }
#pragma unroll
  for (int k = 0; k < 6; ++k) fS[k] = -1e30f;

  const int jstart = (half << 11) | (wave << 9);
  const unsigned short* fa = frag + (((size_t)b * 256 + (jstart >> 4)) * 8) * 512 + (size_t)lane * 8;
  const float2* jbb = jBg + base;

  short8_t A0d[4], A0w[4], A1d[4], A1w[4];
#pragma unroll
  for (int kc = 0; kc < 4; ++kc) {
    A0d[kc] = *(const short8_t*)(fa + kc * 512);
    A0w[kc] = *(const short8_t*)(fa + (4 + kc) * 512);
  }
  float4 n0a = *(const float4*)(jbb + jstart + (quad << 2));
  float4 n0b = *(const float4*)(jbb + jstart + (quad << 2) + 2);
  float4 n1a, n1b;

  for (int t = 0; t < 32; t += 2) {
    const unsigned short* f1 = fa + 4096;            // tile t+1
#pragma unroll
    for (int kc = 0; kc < 4; ++kc) {
      A1d[kc] = *(const short8_t*)(f1 + kc * 512);
      A1w[kc] = *(const short8_t*)(f1 + (4 + kc) * 512);
    }
    {
      const int j1 = jstart + ((t + 1) << 4);
      n1a = *(const float4*)(jbb + j1 + (quad << 2));
      n1b = *(const float4*)(jbb + j1 + (quad << 2) + 2);
    }
    TILE_COMPUTE(A0d, A0w, n0a, n0b, jstart + (t << 4));
    const unsigned short* f2 = fa + ((t + 2 < 32) ? 8192 : 0);   // tile t+2
#pragma unroll
    for (int kc = 0; kc < 4; ++kc) {
      A0d[kc] = *(const short8_t*)(f2 + kc * 512);
      A0w[kc] = *(const short8_t*)(f2 + (4 + kc) * 512);
    }
    {
      const int j2 = jstart + (((t + 2) & 31) << 4);
      n0a = *(const float4*)(jbb + j2 + (quad << 2));
      n0b = *(const float4*)(jbb + j2 + (quad << 2) + 2);
    }
    TILE_COMPUTE(A1d, A1w, n1a, n1b, jstart + ((t + 1) << 4));
    fa += 8192;
  }

  // expand to merge sizes 6/6/10
  float eD[6], eDt[6], eS[10];
#pragma unroll
  for (int k = 0; k < 4; ++k) { eD[k] = fD[k]; eDt[k] = fDt[k]; }
  eD[4] = eD[5] = eDt[4] = eDt[5] = -1e30f;
#pragma unroll
  for (int k = 0; k < 6; ++k) eS[k] = fS[k];
  eS[6] = eS[7] = eS[8] = eS[9] = -1e30f;

  // merge the 4 quads (same anchor class) via shfl butterfly (snapshot first)
  {
    float tmp[10];
#pragma unroll
    for (int off = 16; off <= 32; off <<= 1) {
#pragma unroll
      for (int k = 0; k < 6; ++k) tmp[k] = eD[k];
#pragma unroll
      for (int k = 0; k < 6; ++k) ins6m(__shfl_xor(tmp[k], off, 64), eD);
#pragma unroll
      for (int k = 0; k < 6; ++k) tmp[k] = eDt[k];
#pragma unroll
      for (int k = 0; k < 6; ++k) ins6m(__shfl_xor(tmp[k], off, 64), eDt);
#pragma unroll
      for (int k = 0; k < 10; ++k) tmp[k] = eS[k];
#pragma unroll
      for (int k = 0; k < 10; ++k) ins10m(__shfl_xor(tmp[k], off, 64), eS);
    }
  }

  // ladder merge across 4 waves
#pragma unroll
  for (int h2 = 2; h2 >= 1; h2 >>= 1) {
    if (wave >= h2 && wave < 2 * h2 && lane < 16) {
      float* m = &mb[wave][lane][0];
#pragma unroll
      for (int k = 0; k < 6; ++k) { m[k] = eD[k]; m[6 + k] = eDt[k]; }
#pragma unroll
      for (int k = 0; k < 10; ++k) m[12 + k] = eS[k];
    }
    __syncthreads();
    if (wave < h2 && lane < 16) {
      const float* m = &mb[wave + h2][lane][0];
#pragma unroll
      for (int k = 0; k < 6; ++k) ins6m(m[k], eD);
#pragma unroll
      for (int k = 0; k < 6; ++k) ins6m(m[6 + k], eDt);
#pragma unroll
      for (int k = 0; k < 10; ++k) ins10m(m[12 + k], eS);
    }
  }

  if (wave == 0 && lane < 16) {
    float* P = parts + (size_t)(half * 24) * 8192 + (base + i0 + lane);
#pragma unroll
    for (int k = 0; k < 6; ++k) {
      P[(size_t)k * 8192] = eD[k];
      P[(size_t)(6 + k) * 8192] = eDt[k];
    }
#pragma unroll
    for (int k = 0; k < 10; ++k) P[(size_t)(12 + k) * 8192] = eS[k];
  }
}

__device__ __forceinline__ float bflo(unsigned int u) { return __uint_as_float(u << 16); }
__device__ __forceinline__ float bfhi(unsigned int u) { return __uint_as_float(u & 0xFFFF0000u); }

// 256 blocks x 256 threads; block = 32 anchors. Merge 2 half-segments,
// post-filter, recompute d22 for SOS survivors, accumulate; last block finalizes.
__global__ __launch_bounds__(256) void merge_filter(
    const float* __restrict__ parts, const float4* __restrict__ jAg,
    const float2* __restrict__ jBg, const float* __restrict__ posg,
    const float* __restrict__ visg, const unsigned short* __restrict__ wdb,
    float* __restrict__ accum, float* __restrict__ out) {
  __shared__ int sJ[256];
  __shared__ float sD11[256], sD22[256], sFos[32], sVis[32], sN2[32];
  const int tid = threadIdx.x;
  const int a0 = blockIdx.x * 32;

  if (tid < 32) {
    const int a = a0 + tid;
    const int base = a & ~(NPTS - 1);
    float fD[6], fDt[6], fS[10];
    const float* P = parts + a;
#pragma unroll
    for (int k = 0; k < 6; ++k) { fD[k] = P[(size_t)k * 8192]; fDt[k] = P[(size_t)(6 + k) * 8192]; }
#pragma unroll
    for (int k = 0; k < 10; ++k) fS[k] = P[(size_t)(12 + k) * 8192];
    {
      const float* Q = P + (size_t)24 * 8192;
#pragma unroll
      for (int k = 0; k < 6; ++k) {
        ins6m(Q[(size_t)k * 8192], fD);
        ins6m(Q[(size_t)(6 + k) * 8192], fDt);
      }
#pragma unroll
      for (int k = 0; k < 10; ++k) ins10m(Q[(size_t)(12 + k) * 8192], fS);
    }

    const float4 own = jAg[a];
    const float2 nb = jBg[a];
    const float pv = posg[a], vv = visg[a];
    float t1s = 0.0f, t2s = 0.0f;
    int got = 0;
#pragma unroll
    for (int k = 0; k < 6; ++k) {
      int j = (int)(__float_as_uint(fD[k]) & 0xFFFu);
      float4 jc = jAg[base + j];
      float dz = own.z - jc.z, dw = own.w - jc.w;
      if (got < 4 && dz * dz + dw * dw > 256.0f) {
        float d2 = nb.x - fD[k];
        t1s += fmaxf(1.0f + pv - sqrtf(fmaxf(d2, 1e-12f)), 0.0f);
        got++;
      }
    }
    got = 0;
#pragma unroll
    for (int k = 0; k < 6; ++k) {
      int j = (int)(__float_as_uint(fDt[k]) & 0xFFFu);
      float4 jc = jAg[base + j];
      float dz = own.z - jc.z, dw = own.w - jc.w;
      if (got < 4 && dz * dz + dw * dw > 256.0f) {
        float d2 = nb.y - fDt[k];
        t2s += fmaxf(1.0f + pv - sqrtf(fmaxf(d2, 1e-12f)), 0.0f);
        got++;
      }
    }
    int m = 0;
#pragma unroll
    for (int k = 0; k < 10; ++k) {
      int j = (int)(__float_as_uint(fS[k]) & 0xFFFu);
      float4 jc = jAg[base + j];
      float ay = own.x - jc.x, ax = own.y - jc.y;
      float wz = own.z - jc.z, ww = own.w - jc.w;
      if (m < 8 && ay * ay + ax * ax > 256.0f && wz * wz + ww * ww > 256.0f) {
        sJ[tid * 8 + m] = base + j;
        sD11[tid * 8 + m] = sqrtf(fmaxf(nb.x - fS[k], 1e-12f));
        m++;
      }
    }
    for (int k = m; k < 8; ++k) sJ[tid * 8 + k] = -1;
    sFos[tid] = vv * 0.125f * (t1s + t2s);
    sVis[tid] = vv;
    sN2[tid] = nb.y;
  }
  __syncthreads();

  // d22 for survivors: 256 slots, one thread each
  {
    const int slot = tid;
    const int al = slot >> 3;
    const int j = sJ[slot];
    float d22 = 0.0f;
    if (j >= 0) {
      const uint4* pi = (const uint4*)(wdb + (size_t)(a0 + al) * CDIM);
      const uint4* pj = (const uint4*)(wdb + (size_t)j * CDIM);
      float dot = 0.0f;
#pragma unroll
      for (int qq = 0; qq < 16; ++qq) {
        uint4 ui = pi[qq], uj = pj[qq];
        dot = fmaf(bflo(ui.x), bflo(uj.x), dot); dot = fmaf(bfhi(ui.x), bfhi(uj.x), dot);
        dot = fmaf(bflo(ui.y), bflo(uj.y), dot); dot = fmaf(bfhi(ui.y), bfhi(uj.y), dot);
        dot = fmaf(bflo(ui.z), bflo(uj.z), dot); dot = fmaf(bfhi(ui.z), bfhi(uj.z), dot);
        dot = fmaf(bflo(ui.w), bflo(uj.w), dot); dot = fmaf(bfhi(ui.w), bfhi(uj.w), dot);
      }
      d22 = sqrtf(fmaxf(sN2[al] + jBg[j].y - 2.0f * dot, 1e-12f));
    }
    sD22[slot] = d22;
  }
  __syncthreads();

  float contrib = 0.0f, vsum = 0.0f;
  if (tid < 32) {
    float s = 0.0f;
#pragma unroll
    for (int k = 0; k < 8; ++k) {
      if (sJ[tid * 8 + k] >= 0) {
        float d = sD11[tid * 8 + k] - sD22[tid * 8 + k];
        s = fmaf(d, d, s);
      }
    }
    contrib = sFos[tid] + sVis[tid] * sqrtf(s + 1e-12f);
    vsum = sVis[tid];
  }
  if (tid < 64) {
#pragma unroll
    for (int off = 32; off >= 1; off >>= 1) {
      contrib += __shfl_down(contrib, off, 64);
      vsum += __shfl_down(vsum, off, 64);
    }
    if (tid == 0) {
      atomicAdd(&accum[0], contrib);
      atomicAdd(&accum[1], vsum);
      __threadfence();
      float old = atomicAdd(&accum[2], 1.0f);
      if (old == 255.0f) {
        float t = atomicAdd(&accum[0], 0.0f);
        float v = atomicAdd(&accum[1], 0.0f);
        out[0] = t / (v + 1e-8f);
      }
    }
  }
}

extern "C" void kernel_launch(void* const* d_in, const int* in_sizes, int n_in,
                              void* d_out, int out_size, void* d_ws, size_t ws_size,
                              hipStream_t stream) {
  (void)in_sizes; (void)n_in; (void)out_size;
  const float* kp1   = (const float*)d_in[0];
  const float* wkp1  = (const float*)d_in[1];
  const float* desc  = (const float*)d_in[2];
  const float* desc2 = (const float*)d_in[3];
  const float* homo  = (const float*)d_in[4];
  float* ws = (float*)d_ws;
  unsigned short* frag = (unsigned short*)(ws + OFF_FRAG);
  unsigned short* wdb  = (unsigned short*)(ws + OFF_WDB);
  float4* jA = (float4*)(ws + OFF_JA);
  float2* jB = (float2*)(ws + OFF_JB);
  float* pos = ws + OFF_POS;
  float* vis = ws + OFF_VIS;
  float* acc = ws + OFF_ACC;
  float* parts = ws + OFF_PARTS;
  unsigned short* d2t = (unsigned short*)(ws + OFF_D2T);

  if (ws_size >= (size_t)OFF_END * 4) {
    transpose_desc2<<<600, 256, 0, stream>>>(desc2, d2t);
    prep_t<<<2048, 256, 0, stream>>>(kp1, wkp1, desc, d2t, homo,
                                     frag, wdb, jA, jB, pos, vis, acc);
  } else {
    prep_g<<<2048, 256, 0, stream>>>(kp1, wkp1, desc, desc2, homo,
                                     frag, wdb, jA, jB, pos, vis, acc);
  }
  loss_main<<<1024, 256, 0, stream>>>(frag, jB, parts);
  merge_filter<<<256, 256, 0, stream>>>(parts, jA, jB, pos, vis, wdb, acc,
                                        (float*)d_out);
}